// Round 3
// baseline (831.433 us; speedup 1.0000x reference)
//
#include <hip/hip_runtime.h>

// QuantumDenseNet R15: 4-batch packing (h8 / ds_read_b128) + tail commute-skip.
// R14 showed per-batch LDS bytes, not instructions, plus per-pass VALU overhead
// and barriers dominate. Packing 4 batches per amplitude halves per-batch
// barriers / LDS insts / gate fetches / addressing again (pkfma per batch
// unchanged). LDS 7992*16B = 127.9KB -> dynamic LDS + hipFuncSetAttribute,
// 1 block x 16 waves/CU. Fallback: if the attribute call fails, launch the
// 2-batch (h4) instantiation of the same templated body (63.9KB dynamic).
// Tail skip: final (l=3,hf=1) BS passes 7 (3,4), 9 (2,3) and Dp on modes
// 2,3,4 commute with the X0/X1 measurement -> skipped (5 of 120 passes).

typedef float    vf2 __attribute__((ext_vector_type(2)));
typedef _Float16 h2  __attribute__((ext_vector_type(2)));
typedef _Float16 h4  __attribute__((ext_vector_type(4)));
typedef _Float16 h8  __attribute__((ext_vector_type(8)));

__device__ __forceinline__ h2 pkfma(const h2 a, const h2 b, const h2 c) {
    return __builtin_elementwise_fma(a, b, c);
}

__device__ __forceinline__ void cmadd(float &ax, float &ay, const float2 u, const float2 v) {
    ax = fmaf(u.x, v.x, ax);
    ax = fmaf(-u.y, v.y, ax);
    ay = fmaf(u.x, v.y, ay);
    ay = fmaf(u.y, v.x, ay);
}

// block-diagonal structure of the 36x36 BS gate (total photon number n=0..10)
constexpr int BS_SN[11]  = {1,2,3,4,5,6,5,4,3,2,1};
constexpr int BS_OFF[11] = {0,1,5,14,30,55,91,116,132,141,145};
// mode strides (amp units): {6, 1, 36, 221, 1334} -- mode3/4 padded for banks

// runtime-indexed copy for gates_kernel packing
__device__ const int d_BS_OFF[12] = {0,1,5,14,30,55,91,116,132,141,145,146};
__device__ const int d_BS_SN[11]  = {1,2,3,4,5,6,5,4,3,2,1};

template<int P> struct VecT;
template<> struct VecT<2> { typedef h4 type; };
template<> struct VecT<4> { typedef h8 type; };

// ---------------------------------------------------------------------------
// Gate precompute: blocks 0..79 -> BS gates packed block-diag as BROADCAST h2
// pairs {ur,ur},{ui,ui} (292 h2/gate); block 80 -> 40 single-mode combined
// gates (72 h2/gate), same broadcast packing.
// ---------------------------------------------------------------------------
__global__ void gates_kernel(const float* __restrict__ lin,
                             const float* __restrict__ act,
                             const float* __restrict__ lact,
                             h2* __restrict__ bsh,
                             h2* __restrict__ sgh)
{
    __shared__ float2 B0[1296];
    __shared__ float2 B1[1296];
    const int tid = threadIdx.x;

    if (blockIdx.x < 80) {
        const int g = blockIdx.x;
        const int l = g / 20;
        const int w = g % 20;
        const int q = w / 10;
        const int n = w % 10;
        const float theta = lin[l*63 + (q ? 29 : 0) + n];
        const float phi   = lin[l*63 + (q ? 39 : 10) + n];
        const float ts = theta * 0.015625f;
        const float cp = cosf(phi), sp = sinf(phi);
        const float2 u  = make_float2( ts*cp, ts*sp);
        const float2 w2 = make_float2(-ts*cp, ts*sp);

        float2 *R = B0, *T = B1;
        for (int e = tid; e < 1296; e += 256)
            R[e] = make_float2((e % 37 == 0) ? 1.f : 0.f, 0.f);
        __syncthreads();

        for (int k = 16; k >= 1; --k) {
            const float invk = 1.f / (float)k;
            for (int e = tid; e < 1296; e += 256) {
                const int row = e / 36, c = e - row*36;
                const int i = row / 6, j = row - (row/6)*6;
                float ax = 0.f, ay = 0.f;
                if (i < 5 && j > 0) {
                    const float coef = sqrtf((float)((i+1)*j));
                    const float2 x = R[(row+5)*36 + c];
                    const float px = u.x*x.x - u.y*x.y;
                    const float py = u.x*x.y + u.y*x.x;
                    ax = fmaf(coef, px, ax); ay = fmaf(coef, py, ay);
                }
                if (i > 0 && j < 5) {
                    const float coef = sqrtf((float)(i*(j+1)));
                    const float2 x = R[(row-5)*36 + c];
                    const float px = w2.x*x.x - w2.y*x.y;
                    const float py = w2.x*x.y + w2.y*x.x;
                    ax = fmaf(coef, px, ax); ay = fmaf(coef, py, ay);
                }
                T[e] = make_float2(((row == c) ? 1.f : 0.f) + ax*invk, ay*invk);
            }
            __syncthreads();
            float2* tmp = R; R = T; T = tmp;
        }
        for (int s2 = 0; s2 < 6; ++s2) {
            for (int e = tid; e < 1296; e += 256) {
                const int row = e / 36, c = e - row*36;
                float ax = 0.f, ay = 0.f;
                #pragma unroll 6
                for (int k = 0; k < 36; ++k)
                    cmadd(ax, ay, R[row*36 + k], R[k*36 + c]);
                T[e] = make_float2(ax, ay);
            }
            __syncthreads();
            float2* tmp = R; R = T; T = tmp;
        }
        for (int idx = tid; idx < 146; idx += 256) {
            int nn = 0;
            while (idx >= d_BS_OFF[nn+1]) ++nn;
            const int sn  = d_BS_SN[nn];
            const int rel = idx - d_BS_OFF[nn];
            const int p = rel / sn, qq = rel % sn;
            const int imin = (nn > 5) ? (nn - 5) : 0;
            const int row = 5*(imin + p)  + nn;
            const int col = 5*(imin + qq) + nn;
            const float2 z = R[row*36 + col];
            bsh[g*292 + 2*idx    ] = (h2){(_Float16)z.x, (_Float16)z.x};
            bsh[g*292 + 2*idx + 1] = (h2){(_Float16)z.y, (_Float16)z.y};
        }
    } else {
        const int t = tid;
        if (t >= 40) return;
        const int l  = t / 10;
        const int gi = t % 10;
        float2 G[36];
        if (gi < 5) {
            // Sq[m] = squeeze(r) @ diag(e^{i rphi1 * n})  (parity-banded)
            const int m = gi;
            const float r    = lin[l*63 + 24 + m];
            const float rphi = (m < 4) ? lin[l*63 + 20 + m] : 0.f;
            float R[36], T[36];
            #pragma unroll
            for (int e = 0; e < 36; ++e) R[e] = (e % 7 == 0) ? 1.f : 0.f;
            float hp[4];
            #pragma unroll
            for (int i = 0; i < 4; ++i)
                hp[i] = 0.5f * r * sqrtf((float)((i+1)*(i+2))) * 0.015625f;
            for (int k = 16; k >= 1; --k) {
                const float invk = 1.f / (float)k;
                #pragma unroll
                for (int i = 0; i < 6; ++i) {
                    #pragma unroll
                    for (int c = 0; c < 6; ++c) {
                        float a = 0.f;
                        if (i < 4)  a = fmaf( hp[i],   R[(i+2)*6 + c], a);
                        if (i >= 2) a = fmaf(-hp[i-2], R[(i-2)*6 + c], a);
                        T[i*6+c] = ((i == c) ? 1.f : 0.f) + a*invk;
                    }
                }
                #pragma unroll
                for (int e = 0; e < 36; ++e) R[e] = T[e];
            }
            for (int s2 = 0; s2 < 6; ++s2) {
                #pragma unroll
                for (int i = 0; i < 6; ++i) {
                    #pragma unroll
                    for (int c = 0; c < 6; ++c) {
                        float a = 0.f;
                        #pragma unroll
                        for (int k = 0; k < 6; ++k) a = fmaf(R[i*6+k], R[k*6+c], a);
                        T[i*6+c] = a;
                    }
                }
                #pragma unroll
                for (int e = 0; e < 36; ++e) R[e] = T[e];
            }
            #pragma unroll
            for (int c = 0; c < 6; ++c) {
                const float cc = cosf(rphi * (float)c), ss = sinf(rphi * (float)c);
                #pragma unroll
                for (int o = 0; o < 6; ++o)
                    G[o*6 + c] = make_float2(R[o*6+c]*cc, R[o*6+c]*ss);
            }
        } else {
            // Dp[m] = diag(e^{i kap n^2}) @ disp(dr,dp) @ diag(e^{i rphi2 n})
            const int m = gi - 5;
            const float dr   = lin[l*63 + 53 + m];
            const float dp   = lin[l*63 + 58 + m];
            const float rphi = (m < 4) ? lin[l*63 + 49 + m] : 0.f;
            const float kap  = (l < 3) ? act[l*5 + m] : ((m < 2) ? lact[m] : 0.f);
            const float2 al = make_float2(dr * cosf(dp), dr * sinf(dp));
            float2 R[36], T[36];
            #pragma unroll
            for (int e = 0; e < 36; ++e)
                R[e] = make_float2((e % 7 == 0) ? 1.f : 0.f, 0.f);
            float2 cm[6], cpb[6];
            #pragma unroll
            for (int i = 0; i < 6; ++i) {
                const float sm  = sqrtf((float)i)     * 0.015625f;
                const float sp2 = sqrtf((float)(i+1)) * 0.015625f;
                cm[i]  = make_float2( al.x*sm,  al.y*sm);
                cpb[i] = make_float2(-al.x*sp2, al.y*sp2);
            }
            for (int k = 16; k >= 1; --k) {
                const float invk = 1.f / (float)k;
                #pragma unroll
                for (int i = 0; i < 6; ++i) {
                    #pragma unroll
                    for (int c = 0; c < 6; ++c) {
                        float ax = 0.f, ay = 0.f;
                        if (i >= 1) cmadd(ax, ay, cm[i],  R[(i-1)*6 + c]);
                        if (i < 5)  cmadd(ax, ay, cpb[i], R[(i+1)*6 + c]);
                        T[i*6+c] = make_float2(((i == c) ? 1.f : 0.f) + ax*invk, ay*invk);
                    }
                }
                #pragma unroll
                for (int e = 0; e < 36; ++e) R[e] = T[e];
            }
            for (int s2 = 0; s2 < 6; ++s2) {
                #pragma unroll
                for (int i = 0; i < 6; ++i) {
                    #pragma unroll
                    for (int c = 0; c < 6; ++c) {
                        float ax = 0.f, ay = 0.f;
                        #pragma unroll
                        for (int k = 0; k < 6; ++k) cmadd(ax, ay, R[i*6+k], R[k*6+c]);
                        T[i*6+c] = make_float2(ax, ay);
                    }
                }
                #pragma unroll
                for (int e = 0; e < 36; ++e) R[e] = T[e];
            }
            #pragma unroll
            for (int o = 0; o < 6; ++o) {
                const float ko = kap * (float)(o*o);
                const float2 kp = make_float2(cosf(ko), sinf(ko));
                #pragma unroll
                for (int c = 0; c < 6; ++c) {
                    const float rc = rphi * (float)c;
                    const float2 rp = make_float2(cosf(rc), sinf(rc));
                    const float2 z = R[o*6 + c];
                    const float2 t1 = make_float2(kp.x*z.x - kp.y*z.y, kp.x*z.y + kp.y*z.x);
                    G[o*6 + c] = make_float2(t1.x*rp.x - t1.y*rp.y, t1.x*rp.y + t1.y*rp.x);
                }
            }
        }
        h2* outp = sgh + (l*10 + gi)*72;
        #pragma unroll
        for (int e = 0; e < 36; ++e) {
            outp[2*e    ] = (h2){(_Float16)G[e].x, (_Float16)G[e].x};
            outp[2*e + 1] = (h2){(_Float16)G[e].y, (_Float16)G[e].y};
        }
    }
}

// ---------------------------------------------------------------------------
// Initial displacement (phi=0 -> real expm): column 0 per (batch, mode).
// ---------------------------------------------------------------------------
__global__ void dcol_kernel(const float* __restrict__ x,
                            float* __restrict__ dcol, const int total)
{
    const int i = blockIdx.x * 256 + threadIdx.x;
    if (i >= total) return;
    const float xv = x[i];
    float a[5];
    #pragma unroll
    for (int j = 0; j < 5; ++j) a[j] = xv * sqrtf((float)(j+1)) * 0.015625f;
    float R[36], T[36];
    #pragma unroll
    for (int e = 0; e < 36; ++e) R[e] = (e % 7 == 0) ? 1.f : 0.f;
    for (int k = 16; k >= 1; --k) {
        const float invk = 1.f / (float)k;
        #pragma unroll
        for (int r = 0; r < 6; ++r) {
            #pragma unroll
            for (int c = 0; c < 6; ++c) {
                float acc = 0.f;
                if (r >= 1) acc = fmaf( a[r-1], R[(r-1)*6 + c], acc);
                if (r < 5)  acc = fmaf(-a[r],   R[(r+1)*6 + c], acc);
                T[r*6+c] = ((r == c) ? 1.f : 0.f) + acc*invk;
            }
        }
        #pragma unroll
        for (int e = 0; e < 36; ++e) R[e] = T[e];
    }
    for (int s2 = 0; s2 < 6; ++s2) {
        #pragma unroll
        for (int r = 0; r < 6; ++r) {
            #pragma unroll
            for (int c = 0; c < 6; ++c) {
                float acc = 0.f;
                #pragma unroll
                for (int k = 0; k < 6; ++k) acc = fmaf(R[r*6+k], R[k*6+c], acc);
                T[r*6+c] = acc;
            }
        }
        #pragma unroll
        for (int e = 0; e < 36; ++e) R[e] = T[e];
    }
    #pragma unroll
    for (int j = 0; j < 6; ++j) dcol[i*6 + j] = R[j*6 + 0];
}

// ---------------------------------------------------------------------------
// Main kernel building blocks (P batches packed per amplitude; W = P/2 h2
// words per re/im component). Amp layout: [re words][im words].
// ---------------------------------------------------------------------------

template<int P>
__device__ __forceinline__ void ampLoad(const typename VecT<P>::type* __restrict__ psi,
                                        const int idx, h2* R, h2* I)
{
    const auto v = psi[idx];
    if constexpr (P == 2) {
        R[0] = __builtin_shufflevector(v, v, 0, 1);
        I[0] = __builtin_shufflevector(v, v, 2, 3);
    } else {
        R[0] = __builtin_shufflevector(v, v, 0, 1);
        R[1] = __builtin_shufflevector(v, v, 2, 3);
        I[0] = __builtin_shufflevector(v, v, 4, 5);
        I[1] = __builtin_shufflevector(v, v, 6, 7);
    }
}

template<int P>
__device__ __forceinline__ typename VecT<P>::type ampPack(const h2* R, const h2* I)
{
    if constexpr (P == 2) {
        return (h4){R[0].x, R[0].y, I[0].x, I[0].y};
    } else {
        return (h8){R[0].x, R[0].y, R[1].x, R[1].y,
                    I[0].x, I[0].y, I[1].x, I[1].y};
    }
}

// first cMAC term (mul) and accumulating cMAC term
template<int W>
__device__ __forceinline__ void cmul2(const h2 ur, const h2 ui,
                                      const h2* vR, const h2* vI, h2* aR, h2* aI)
{
    #pragma unroll
    for (int w = 0; w < W; ++w) {
        aR[w] = ur * vR[w];
        aR[w] = pkfma(-ui, vI[w], aR[w]);
        aI[w] = ur * vI[w];
        aI[w] = pkfma(ui, vR[w], aI[w]);
    }
}
template<int W>
__device__ __forceinline__ void cmac2(const h2 ur, const h2 ui,
                                      const h2* vR, const h2* vI, h2* aR, h2* aI)
{
    #pragma unroll
    for (int w = 0; w < W; ++w) {
        aR[w] = pkfma(ur, vR[w], aR[w]);
        aR[w] = pkfma(-ui, vI[w], aR[w]);
        aI[w] = pkfma(ur, vI[w], aI[w]);
        aI[w] = pkfma(ui, vR[w], aI[w]);
    }
}

// rows [R0,R1) of photon block n of one BS pass.
template<int P, int SA, int SB, int n, int R0, int R1>
__device__ __forceinline__ void bs_rows(const h2* __restrict__ U,
                                        typename VecT<P>::type* __restrict__ psi,
                                        const int base, const bool act)
{
    constexpr int W = P/2;
    constexpr int sn = BS_SN[n], uoff = BS_OFF[n];
    constexpr int imin = (n > 5) ? (n - 5) : 0;
    if (!act) return;
    h2 vR[sn][W], vI[sn][W];
    #pragma unroll
    for (int q = 0; q < sn; ++q) {
        const int c = 5*(imin + q) + n;
        ampLoad<P>(psi, base + (c/6)*SA + (c%6)*SB, vR[q], vI[q]);
    }
    h2 oR[R1-R0][W], oI[R1-R0][W];
    #pragma unroll
    for (int p = R0; p < R1; ++p) {
        const h2* Up = U + 2*(uoff + p*sn);
        cmul2<W>(Up[0], Up[1], vR[0], vI[0], oR[p-R0], oI[p-R0]);
        #pragma unroll
        for (int q = 1; q < sn; ++q)
            cmac2<W>(Up[2*q], Up[2*q + 1], vR[q], vI[q], oR[p-R0], oI[p-R0]);
    }
    #pragma unroll
    for (int p = R0; p < R1; ++p) {
        const int c = 5*(imin + p) + n;
        psi[base + (c/6)*SA + (c%6)*SB] = ampPack<P>(oR[p-R0], oI[p-R0]);
    }
}

// BS pass: 4 wave-aligned quarters of 256 threads; whole-block groups (no row
// splits -- those race on read-vs-write of shared block inputs).
// packed-cMAC: q0={5}=36, q1={4,2,1}=38, q2={6,8,9}=38, q3={3,7,0,10}=34.
template<int P, int SA, int SB>
__device__ __forceinline__ void pass_bs(const h2* __restrict__ U,
                                        typename VecT<P>::type* __restrict__ psi,
                                        const int base, const bool act, const int qid)
{
    if (qid == 0) {
        bs_rows<P,SA,SB,5,0,6>(U, psi, base, act);
    } else if (qid == 1) {
        bs_rows<P,SA,SB,4,0,5>(U, psi, base, act);
        bs_rows<P,SA,SB,2,0,3>(U, psi, base, act);
        bs_rows<P,SA,SB,1,0,2>(U, psi, base, act);
    } else if (qid == 2) {
        bs_rows<P,SA,SB,6,0,5>(U, psi, base, act);
        bs_rows<P,SA,SB,8,0,3>(U, psi, base, act);
        bs_rows<P,SA,SB,9,0,2>(U, psi, base, act);
    } else {
        bs_rows<P,SA,SB,3,0,4>(U, psi, base, act);
        bs_rows<P,SA,SB,7,0,4>(U, psi, base, act);
        bs_rows<P,SA,SB,0,0,1>(U, psi, base, act);
        bs_rows<P,SA,SB,10,0,1>(U, psi, base, act);
    }
    __syncthreads();
}

// one single-mode-gate fiber (6 amplitudes, stride SM)
template<int P, int SM, bool SP>
__device__ __forceinline__ void sg_fiber(const h2* __restrict__ G,
                                         typename VecT<P>::type* __restrict__ psi,
                                         const int base)
{
    constexpr int W = P/2;
    h2 vR[6][W], vI[6][W];
    #pragma unroll
    for (int k = 0; k < 6; ++k)
        ampLoad<P>(psi, base + k*SM, vR[k], vI[k]);
    h2 oR[6][W], oI[6][W];
    #pragma unroll
    for (int o = 0; o < 6; ++o) {
        const int k0 = SP ? (o & 1) : 0;
        const int st = SP ? 2 : 1;
        cmul2<W>(G[2*(o*6 + k0)], G[2*(o*6 + k0) + 1], vR[k0], vI[k0], oR[o], oI[o]);
        #pragma unroll
        for (int k = k0 + st; k < 6; k += st)
            cmac2<W>(G[2*(o*6 + k)], G[2*(o*6 + k) + 1], vR[k], vI[k], oR[o], oI[o]);
    }
    #pragma unroll
    for (int o = 0; o < 6; ++o)
        psi[base + o*SM] = ampPack<P>(oR[o], oI[o]);
}

// single-mode gate pass: 1296 fibers over 1024 threads (ragged second round).
template<int P, int SM, int S0, int S1, int S2, int S3, bool SP>
__device__ __forceinline__ void pass_sg(const h2* __restrict__ G,
                                        typename VecT<P>::type* __restrict__ psi,
                                        const int4 dg0, const int4 dg1, const bool act1)
{
    {
        const int base = dg0.x*S0 + dg0.y*S1 + dg0.z*S2 + dg0.w*S3;
        sg_fiber<P,SM,SP>(G, psi, base);
    }
    if (act1) {
        const int base = dg1.x*S0 + dg1.y*S1 + dg1.z*S2 + dg1.w*S3;
        sg_fiber<P,SM,SP>(G, psi, base);
    }
    __syncthreads();
}

__device__ __forceinline__ float hget(const h2 v, const int hi) {
    return (float)(hi ? v.y : v.x);
}

template<int PACK>
__device__ __forceinline__ void qnet_body(const h2* __restrict__ bs,
                                          const h2* __restrict__ sg,
                                          const float* __restrict__ dcol,
                                          float* __restrict__ out,
                                          const int B)
{
    constexpr int W = PACK/2;
    using AT = typename VecT<PACK>::type;
    extern __shared__ __align__(16) char qnet_smem[];
    AT* psi = reinterpret_cast<AT*>(qnet_smem);
    __shared__ float stf[PACK*30];
    __shared__ float red[16*2*PACK];

    const int tid = threadIdx.x;
    const int b   = blockIdx.x;          // batch group [PACK*b, PACK*b+PACK)

    const int lim = B * 30;
    if (tid < PACK*30)
        stf[tid] = (b*PACK*30 + tid < lim) ? dcol[b*PACK*30 + tid] : 0.f;
    __syncthreads();
    for (int e = tid; e < 7776; e += 1024) {
        int t = e;
        const int i4 = t % 6; t /= 6;
        const int i3 = t % 6; t /= 6;
        const int i2 = t % 6; t /= 6;
        const int i1 = t % 6; t /= 6;
        const int i0 = t;
        const int addr = 6*i0 + i1 + 36*i2 + 221*i3 + 1334*i4;
        h2 R[W], I[W];
        #pragma unroll
        for (int p = 0; p < PACK; ++p) {
            const float v = stf[p*30 + i0]*stf[p*30 + 6 + i1]*stf[p*30 + 12 + i2]
                          * stf[p*30 + 18 + i3]*stf[p*30 + 24 + i4];
            if (p & 1) R[p>>1].y = (_Float16)v; else R[p>>1].x = (_Float16)v;
        }
        #pragma unroll
        for (int w = 0; w < W; ++w) I[w] = (h2){(_Float16)0.f, (_Float16)0.f};
        psi[addr] = ampPack<PACK>(R, I);
    }
    __syncthreads();

    // BS mapping: 4 quarters of 256; sub<216 active; fiber f = sub
    const int sub = tid & 255;
    const int qid = __builtin_amdgcn_readfirstlane(tid >> 8);   // wave-uniform
    const bool act = sub < 216;
    const int f = act ? sub : 215;
    const int fa = f / 36, rem = f - fa*36;
    const int fb = rem / 6, fc = rem - fb*6;
    const int baseK0 = fa*36 + fb*221 + fc*1334;   // pair (0,1): spect 2,3,4
    const int baseK1 = fa*6  + fb*221 + fc*1334;   // pair (1,2): spect 0,3,4
    const int baseK2 = rem   + fa*1334;            // pair (2,3): spect 0,1 (contig), 4
    const int baseK3 = f;                          // pair (3,4): spect 0,1,2 (contig)

    // SG mapping: fibers tid and tid+1024 (<1296); digits precomputed once
    int4 dg0, dg1;
    { int t = tid;        dg0.x = t % 6; t /= 6; dg0.y = t % 6; t /= 6; dg0.z = t % 6; dg0.w = t / 6; }
    { int t = tid + 1024; dg1.x = t % 6; t /= 6; dg1.y = t % 6; t /= 6; dg1.z = t % 6; dg1.w = t / 6; }
    const bool act1 = tid < 272;

    for (int l = 0; l < 4; ++l) {
        const h2* bsl = bs + l * 20 * 292;
        const h2* sgl = sg + l * 10 * 72;
        for (int hf = 0; hf < 2; ++hf) {
            const h2* bh = bsl + hf * 10 * 292;
            const h2* sh = sgl + hf * 5 * 72;
            // tail skip: in the final half-layer, gates acting only on modes
            // {2,3,4} commute with the X0/X1 measurement -> drop them.
            const bool last = (l == 3) && (hf == 1);
            // rail order k = {0,2,1,3,0,2,1,3,0,2}
            pass_bs<PACK,6,1>     (bh + 0*292, psi, baseK0, act, qid);
            pass_bs<PACK,36,221>  (bh + 1*292, psi, baseK2, act, qid);
            pass_bs<PACK,1,36>    (bh + 2*292, psi, baseK1, act, qid);
            pass_bs<PACK,221,1334>(bh + 3*292, psi, baseK3, act, qid);
            pass_bs<PACK,6,1>     (bh + 4*292, psi, baseK0, act, qid);
            pass_bs<PACK,36,221>  (bh + 5*292, psi, baseK2, act, qid);
            pass_bs<PACK,1,36>    (bh + 6*292, psi, baseK1, act, qid);
            if (!last)
                pass_bs<PACK,221,1334>(bh + 7*292, psi, baseK3, act, qid);
            pass_bs<PACK,6,1>     (bh + 8*292, psi, baseK0, act, qid);
            if (!last)
                pass_bs<PACK,36,221>  (bh + 9*292, psi, baseK2, act, qid);
            if (hf == 0) {   // squeeze gates: parity-sparse
                pass_sg<PACK,6,    1,36,221,1334, true>(sh + 0*72, psi, dg0, dg1, act1);
                pass_sg<PACK,1,    6,36,221,1334, true>(sh + 1*72, psi, dg0, dg1, act1);
                pass_sg<PACK,36,   1,6,221,1334,  true>(sh + 2*72, psi, dg0, dg1, act1);
                pass_sg<PACK,221,  1,6,36,1334,   true>(sh + 3*72, psi, dg0, dg1, act1);
                pass_sg<PACK,1334, 1,6,36,221,    true>(sh + 4*72, psi, dg0, dg1, act1);
            } else {         // displacement gates: dense
                pass_sg<PACK,6,    1,36,221,1334, false>(sh + 0*72, psi, dg0, dg1, act1);
                pass_sg<PACK,1,    6,36,221,1334, false>(sh + 1*72, psi, dg0, dg1, act1);
                if (!last) {
                    pass_sg<PACK,36,   1,6,221,1334,  false>(sh + 2*72, psi, dg0, dg1, act1);
                    pass_sg<PACK,221,  1,6,36,1334,   false>(sh + 3*72, psi, dg0, dg1, act1);
                    pass_sg<PACK,1334, 1,6,36,221,    false>(sh + 4*72, psi, dg0, dg1, act1);
                }
            }
        }
    }

    // <psi| X psi> on modes 0 (stride 6) and 1 (stride 1); per-batch f32 accum
    float s0[PACK], s1[PACK];
    #pragma unroll
    for (int p = 0; p < PACK; ++p) { s0[p] = 0.f; s1[p] = 0.f; }
    for (int fr = tid; fr < 1296; fr += 1024) {
        const int q0 = fr % 6;
        const int q1 = (fr / 6) % 6;
        const int q2 = (fr / 36) % 6;
        const int q3 = fr / 216;
        const int base0 = q0*1 + q1*36 + q2*221 + q3*1334;   // spectators of mode 0
        #pragma unroll
        for (int j = 0; j < 5; ++j) {
            h2 aR[W], aI[W], cR[W], cI[W];
            ampLoad<PACK>(psi, base0 + 6*j,     aR, aI);
            ampLoad<PACK>(psi, base0 + 6*(j+1), cR, cI);
            const float wj = sqrtf((float)(j+1));
            #pragma unroll
            for (int p = 0; p < PACK; ++p) {
                const int w = p >> 1, hi = p & 1;
                s0[p] = fmaf(wj, fmaf(hget(aI[w],hi), hget(cI[w],hi),
                                      hget(aR[w],hi)*hget(cR[w],hi)), s0[p]);
            }
        }
        const int base1 = q0*6 + q1*36 + q2*221 + q3*1334;   // spectators of mode 1
        #pragma unroll
        for (int j = 0; j < 5; ++j) {
            h2 aR[W], aI[W], cR[W], cI[W];
            ampLoad<PACK>(psi, base1 + j,     aR, aI);
            ampLoad<PACK>(psi, base1 + j + 1, cR, cI);
            const float wj = sqrtf((float)(j+1));
            #pragma unroll
            for (int p = 0; p < PACK; ++p) {
                const int w = p >> 1, hi = p & 1;
                s1[p] = fmaf(wj, fmaf(hget(aI[w],hi), hget(cI[w],hi),
                                      hget(aR[w],hi)*hget(cR[w],hi)), s1[p]);
            }
        }
    }
    #pragma unroll
    for (int off = 32; off > 0; off >>= 1) {
        #pragma unroll
        for (int p = 0; p < PACK; ++p) {
            s0[p] += __shfl_down(s0[p], off, 64);
            s1[p] += __shfl_down(s1[p], off, 64);
        }
    }
    if ((tid & 63) == 0) {
        const int w = tid >> 6;
        #pragma unroll
        for (int p = 0; p < PACK; ++p) {
            red[w*2*PACK + 2*p    ] = s0[p];
            red[w*2*PACK + 2*p + 1] = s1[p];
        }
    }
    __syncthreads();
    if (tid == 0) {
        #pragma unroll
        for (int p = 0; p < PACK; ++p) {
            float r0 = 0.f, r1 = 0.f;
            for (int w = 0; w < 16; ++w) {
                r0 += red[w*2*PACK + 2*p];
                r1 += red[w*2*PACK + 2*p + 1];
            }
            const int bb = PACK*b + p;
            if (bb < B) {
                out[bb*2 + 0] = 2.f * r0;
                out[bb*2 + 1] = 2.f * r1;
            }
        }
    }
}

__global__ __launch_bounds__(1024, 8)
void qnet_kernel2(const h2* __restrict__ bs, const h2* __restrict__ sg,
                  const float* __restrict__ dcol, float* __restrict__ out, const int B)
{
    qnet_body<2>(bs, sg, dcol, out, B);
}

__global__ __launch_bounds__(1024, 4)
void qnet_kernel4(const h2* __restrict__ bs, const h2* __restrict__ sg,
                  const float* __restrict__ dcol, float* __restrict__ out, const int B)
{
    qnet_body<4>(bs, sg, dcol, out, B);
}

// ---------------------------------------------------------------------------
extern "C" void kernel_launch(void* const* d_in, const int* in_sizes, int n_in,
                              void* d_out, int out_size, void* d_ws, size_t ws_size,
                              hipStream_t stream)
{
    const float* x    = (const float*)d_in[0];   // (B, 5)
    const float* lin  = (const float*)d_in[1];   // (4, 63)
    const float* act  = (const float*)d_in[2];   // (3, 5)
    const float* lact = (const float*)d_in[3];   // (5,)
    float* out = (float*)d_out;                  // (B, 2) float32

    const int B = in_sizes[0] / 5;

    // ws layout: 80 BS gates (292 h2) | 40 single gates (72 h2) | dcol f32
    h2*    bsh = (h2*)d_ws;
    h2*    sgh = bsh + 80*292;
    float* dc  = (float*)(sgh + 40*72);

    // one-time: raise dynamic-LDS cap for the 4-batch kernel (127.9 KB)
    static int use4 = -1;
    if (use4 < 0) {
        hipError_t e = hipFuncSetAttribute(
            reinterpret_cast<const void*>(qnet_kernel4),
            hipFuncAttributeMaxDynamicSharedMemorySize, 131072);
        use4 = (e == hipSuccess) ? 1 : 0;
    }

    gates_kernel<<<dim3(81), dim3(256), 0, stream>>>(lin, act, lact, bsh, sgh);
    const int total = B * 5;
    dcol_kernel<<<dim3((total + 255)/256), dim3(256), 0, stream>>>(x, dc, total);
    if (use4) {
        qnet_kernel4<<<dim3((B + 3) / 4), dim3(1024), 7992*16, stream>>>(bsh, sgh, dc, out, B);
    } else {
        qnet_kernel2<<<dim3((B + 1) / 2), dim3(1024), 7992*8, stream>>>(bsh, sgh, dc, out, B);
    }
}

// Round 4
// 784.275 us; speedup vs baseline: 1.0601x; 1.0601x over previous
//
#include <hip/hip_runtime.h>

// QuantumDenseNet R16: PACK=2 topology restored (R15's PACK=4 lost 2-block/CU
// barrier overlap: occupancy 47%, VALUBusy 67). Keeps R15's verified tail
// commute-skip. New: zero-cost bank-pair residue rebalancing for ds_*_b64 --
// conflicts were ~2.2k of each ~6.8k-cycle pass interval:
//   * S4 1334 -> 1332 (=4 mod 16): K2's rem + fa*S4 becomes exactly
//     4-lanes-per-bank-pair.
//   * BS K0/K1 fiber digit remap: fastest digit -> stride 221 (only odd
//     stride mod 16, 6 distinct classes), even strides on slow digits.
//   * SG digit->spectator reorder: mode-1 pass had ALL lanes on even
//     bank-pairs (stride-6 fastest); now odd stride fastest.
// All remaps live in once-computed bases / constexpr offsets: 0 loop cost.

typedef float    vf2 __attribute__((ext_vector_type(2)));
typedef _Float16 h2  __attribute__((ext_vector_type(2)));
typedef _Float16 h4  __attribute__((ext_vector_type(4)));

__device__ __forceinline__ h2 pkfma(const h2 a, const h2 b, const h2 c) {
    return __builtin_elementwise_fma(a, b, c);
}

__device__ __forceinline__ void cmadd(float &ax, float &ay, const float2 u, const float2 v) {
    ax = fmaf(u.x, v.x, ax);
    ax = fmaf(-u.y, v.y, ax);
    ay = fmaf(u.x, v.y, ay);
    ay = fmaf(u.y, v.x, ay);
}

// block-diagonal structure of the 36x36 BS gate (total photon number n=0..10)
constexpr int BS_SN[11]  = {1,2,3,4,5,6,5,4,3,2,1};
constexpr int BS_OFF[11] = {0,1,5,14,30,55,91,116,132,141,145};
// mode strides (amp units): {6, 1, 36, 221, 1332}; max addr 7980

// runtime-indexed copy for gates_kernel packing
__device__ const int d_BS_OFF[12] = {0,1,5,14,30,55,91,116,132,141,145,146};
__device__ const int d_BS_SN[11]  = {1,2,3,4,5,6,5,4,3,2,1};

// ---------------------------------------------------------------------------
// Gate precompute: blocks 0..79 -> BS gates packed block-diag as BROADCAST h2
// pairs {ur,ur},{ui,ui} (292 h2/gate); block 80 -> 40 single-mode combined
// gates (72 h2/gate), same broadcast packing.
// ---------------------------------------------------------------------------
__global__ void gates_kernel(const float* __restrict__ lin,
                             const float* __restrict__ act,
                             const float* __restrict__ lact,
                             h2* __restrict__ bsh,
                             h2* __restrict__ sgh)
{
    __shared__ float2 B0[1296];
    __shared__ float2 B1[1296];
    const int tid = threadIdx.x;

    if (blockIdx.x < 80) {
        const int g = blockIdx.x;
        const int l = g / 20;
        const int w = g % 20;
        const int q = w / 10;
        const int n = w % 10;
        const float theta = lin[l*63 + (q ? 29 : 0) + n];
        const float phi   = lin[l*63 + (q ? 39 : 10) + n];
        const float ts = theta * 0.015625f;
        const float cp = cosf(phi), sp = sinf(phi);
        const float2 u  = make_float2( ts*cp, ts*sp);
        const float2 w2 = make_float2(-ts*cp, ts*sp);

        float2 *R = B0, *T = B1;
        for (int e = tid; e < 1296; e += 256)
            R[e] = make_float2((e % 37 == 0) ? 1.f : 0.f, 0.f);
        __syncthreads();

        for (int k = 16; k >= 1; --k) {
            const float invk = 1.f / (float)k;
            for (int e = tid; e < 1296; e += 256) {
                const int row = e / 36, c = e - row*36;
                const int i = row / 6, j = row - (row/6)*6;
                float ax = 0.f, ay = 0.f;
                if (i < 5 && j > 0) {
                    const float coef = sqrtf((float)((i+1)*j));
                    const float2 x = R[(row+5)*36 + c];
                    const float px = u.x*x.x - u.y*x.y;
                    const float py = u.x*x.y + u.y*x.x;
                    ax = fmaf(coef, px, ax); ay = fmaf(coef, py, ay);
                }
                if (i > 0 && j < 5) {
                    const float coef = sqrtf((float)(i*(j+1)));
                    const float2 x = R[(row-5)*36 + c];
                    const float px = w2.x*x.x - w2.y*x.y;
                    const float py = w2.x*x.y + w2.y*x.x;
                    ax = fmaf(coef, px, ax); ay = fmaf(coef, py, ay);
                }
                T[e] = make_float2(((row == c) ? 1.f : 0.f) + ax*invk, ay*invk);
            }
            __syncthreads();
            float2* tmp = R; R = T; T = tmp;
        }
        for (int s2 = 0; s2 < 6; ++s2) {
            for (int e = tid; e < 1296; e += 256) {
                const int row = e / 36, c = e - row*36;
                float ax = 0.f, ay = 0.f;
                #pragma unroll 6
                for (int k = 0; k < 36; ++k)
                    cmadd(ax, ay, R[row*36 + k], R[k*36 + c]);
                T[e] = make_float2(ax, ay);
            }
            __syncthreads();
            float2* tmp = R; R = T; T = tmp;
        }
        for (int idx = tid; idx < 146; idx += 256) {
            int nn = 0;
            while (idx >= d_BS_OFF[nn+1]) ++nn;
            const int sn  = d_BS_SN[nn];
            const int rel = idx - d_BS_OFF[nn];
            const int p = rel / sn, qq = rel % sn;
            const int imin = (nn > 5) ? (nn - 5) : 0;
            const int row = 5*(imin + p)  + nn;
            const int col = 5*(imin + qq) + nn;
            const float2 z = R[row*36 + col];
            bsh[g*292 + 2*idx    ] = (h2){(_Float16)z.x, (_Float16)z.x};
            bsh[g*292 + 2*idx + 1] = (h2){(_Float16)z.y, (_Float16)z.y};
        }
    } else {
        const int t = tid;
        if (t >= 40) return;
        const int l  = t / 10;
        const int gi = t % 10;
        float2 G[36];
        if (gi < 5) {
            // Sq[m] = squeeze(r) @ diag(e^{i rphi1 * n})  (parity-banded)
            const int m = gi;
            const float r    = lin[l*63 + 24 + m];
            const float rphi = (m < 4) ? lin[l*63 + 20 + m] : 0.f;
            float R[36], T[36];
            #pragma unroll
            for (int e = 0; e < 36; ++e) R[e] = (e % 7 == 0) ? 1.f : 0.f;
            float hp[4];
            #pragma unroll
            for (int i = 0; i < 4; ++i)
                hp[i] = 0.5f * r * sqrtf((float)((i+1)*(i+2))) * 0.015625f;
            for (int k = 16; k >= 1; --k) {
                const float invk = 1.f / (float)k;
                #pragma unroll
                for (int i = 0; i < 6; ++i) {
                    #pragma unroll
                    for (int c = 0; c < 6; ++c) {
                        float a = 0.f;
                        if (i < 4)  a = fmaf( hp[i],   R[(i+2)*6 + c], a);
                        if (i >= 2) a = fmaf(-hp[i-2], R[(i-2)*6 + c], a);
                        T[i*6+c] = ((i == c) ? 1.f : 0.f) + a*invk;
                    }
                }
                #pragma unroll
                for (int e = 0; e < 36; ++e) R[e] = T[e];
            }
            for (int s2 = 0; s2 < 6; ++s2) {
                #pragma unroll
                for (int i = 0; i < 6; ++i) {
                    #pragma unroll
                    for (int c = 0; c < 6; ++c) {
                        float a = 0.f;
                        #pragma unroll
                        for (int k = 0; k < 6; ++k) a = fmaf(R[i*6+k], R[k*6+c], a);
                        T[i*6+c] = a;
                    }
                }
                #pragma unroll
                for (int e = 0; e < 36; ++e) R[e] = T[e];
            }
            #pragma unroll
            for (int c = 0; c < 6; ++c) {
                const float cc = cosf(rphi * (float)c), ss = sinf(rphi * (float)c);
                #pragma unroll
                for (int o = 0; o < 6; ++o)
                    G[o*6 + c] = make_float2(R[o*6+c]*cc, R[o*6+c]*ss);
            }
        } else {
            // Dp[m] = diag(e^{i kap n^2}) @ disp(dr,dp) @ diag(e^{i rphi2 n})
            const int m = gi - 5;
            const float dr   = lin[l*63 + 53 + m];
            const float dp   = lin[l*63 + 58 + m];
            const float rphi = (m < 4) ? lin[l*63 + 49 + m] : 0.f;
            const float kap  = (l < 3) ? act[l*5 + m] : ((m < 2) ? lact[m] : 0.f);
            const float2 al = make_float2(dr * cosf(dp), dr * sinf(dp));
            float2 R[36], T[36];
            #pragma unroll
            for (int e = 0; e < 36; ++e)
                R[e] = make_float2((e % 7 == 0) ? 1.f : 0.f, 0.f);
            float2 cm[6], cpb[6];
            #pragma unroll
            for (int i = 0; i < 6; ++i) {
                const float sm  = sqrtf((float)i)     * 0.015625f;
                const float sp2 = sqrtf((float)(i+1)) * 0.015625f;
                cm[i]  = make_float2( al.x*sm,  al.y*sm);
                cpb[i] = make_float2(-al.x*sp2, al.y*sp2);
            }
            for (int k = 16; k >= 1; --k) {
                const float invk = 1.f / (float)k;
                #pragma unroll
                for (int i = 0; i < 6; ++i) {
                    #pragma unroll
                    for (int c = 0; c < 6; ++c) {
                        float ax = 0.f, ay = 0.f;
                        if (i >= 1) cmadd(ax, ay, cm[i],  R[(i-1)*6 + c]);
                        if (i < 5)  cmadd(ax, ay, cpb[i], R[(i+1)*6 + c]);
                        T[i*6+c] = make_float2(((i == c) ? 1.f : 0.f) + ax*invk, ay*invk);
                    }
                }
                #pragma unroll
                for (int e = 0; e < 36; ++e) R[e] = T[e];
            }
            for (int s2 = 0; s2 < 6; ++s2) {
                #pragma unroll
                for (int i = 0; i < 6; ++i) {
                    #pragma unroll
                    for (int c = 0; c < 6; ++c) {
                        float ax = 0.f, ay = 0.f;
                        #pragma unroll
                        for (int k = 0; k < 6; ++k) cmadd(ax, ay, R[i*6+k], R[k*6+c]);
                        T[i*6+c] = make_float2(ax, ay);
                    }
                }
                #pragma unroll
                for (int e = 0; e < 36; ++e) R[e] = T[e];
            }
            #pragma unroll
            for (int o = 0; o < 6; ++o) {
                const float ko = kap * (float)(o*o);
                const float2 kp = make_float2(cosf(ko), sinf(ko));
                #pragma unroll
                for (int c = 0; c < 6; ++c) {
                    const float rc = rphi * (float)c;
                    const float2 rp = make_float2(cosf(rc), sinf(rc));
                    const float2 z = R[o*6 + c];
                    const float2 t1 = make_float2(kp.x*z.x - kp.y*z.y, kp.x*z.y + kp.y*z.x);
                    G[o*6 + c] = make_float2(t1.x*rp.x - t1.y*rp.y, t1.x*rp.y + t1.y*rp.x);
                }
            }
        }
        h2* outp = sgh + (l*10 + gi)*72;
        #pragma unroll
        for (int e = 0; e < 36; ++e) {
            outp[2*e    ] = (h2){(_Float16)G[e].x, (_Float16)G[e].x};
            outp[2*e + 1] = (h2){(_Float16)G[e].y, (_Float16)G[e].y};
        }
    }
}

// ---------------------------------------------------------------------------
// Initial displacement (phi=0 -> real expm): column 0 per (batch, mode).
// ---------------------------------------------------------------------------
__global__ void dcol_kernel(const float* __restrict__ x,
                            float* __restrict__ dcol, const int total)
{
    const int i = blockIdx.x * 256 + threadIdx.x;
    if (i >= total) return;
    const float xv = x[i];
    float a[5];
    #pragma unroll
    for (int j = 0; j < 5; ++j) a[j] = xv * sqrtf((float)(j+1)) * 0.015625f;
    float R[36], T[36];
    #pragma unroll
    for (int e = 0; e < 36; ++e) R[e] = (e % 7 == 0) ? 1.f : 0.f;
    for (int k = 16; k >= 1; --k) {
        const float invk = 1.f / (float)k;
        #pragma unroll
        for (int r = 0; r < 6; ++r) {
            #pragma unroll
            for (int c = 0; c < 6; ++c) {
                float acc = 0.f;
                if (r >= 1) acc = fmaf( a[r-1], R[(r-1)*6 + c], acc);
                if (r < 5)  acc = fmaf(-a[r],   R[(r+1)*6 + c], acc);
                T[r*6+c] = ((r == c) ? 1.f : 0.f) + acc*invk;
            }
        }
        #pragma unroll
        for (int e = 0; e < 36; ++e) R[e] = T[e];
    }
    for (int s2 = 0; s2 < 6; ++s2) {
        #pragma unroll
        for (int r = 0; r < 6; ++r) {
            #pragma unroll
            for (int c = 0; c < 6; ++c) {
                float acc = 0.f;
                #pragma unroll
                for (int k = 0; k < 6; ++k) acc = fmaf(R[r*6+k], R[k*6+c], acc);
                T[r*6+c] = acc;
            }
        }
        #pragma unroll
        for (int e = 0; e < 36; ++e) R[e] = T[e];
    }
    #pragma unroll
    for (int j = 0; j < 6; ++j) dcol[i*6 + j] = R[j*6 + 0];
}

// ---------------------------------------------------------------------------
// Main kernel building blocks (batch-pair packed, 8B complex amplitudes)
// ---------------------------------------------------------------------------

// rows [R0,R1) of photon block n of one BS pass. One ds_read_b64 per input
// amplitude; lo h2 = re{b0,b1}, hi h2 = im{b0,b1}. Broadcast gates:
//   aR += ur*vR - ui*vI ; aI += ur*vI + ui*vR
template<int SA, int SB, int n, int R0, int R1>
__device__ __forceinline__ void bs_rows(const h2* __restrict__ U,
                                        h4* __restrict__ psi,
                                        const int base, const bool act)
{
    constexpr int sn = BS_SN[n], uoff = BS_OFF[n];
    constexpr int imin = (n > 5) ? (n - 5) : 0;
    if (!act) return;
    h2 vR[sn], vI[sn];
    #pragma unroll
    for (int q = 0; q < sn; ++q) {
        const int c = 5*(imin + q) + n;
        const h4 v = psi[base + (c/6)*SA + (c%6)*SB];
        vR[q] = (h2){v.x, v.y};
        vI[q] = (h2){v.z, v.w};
    }
    h2 oR[R1-R0], oI[R1-R0];
    #pragma unroll
    for (int p = R0; p < R1; ++p) {
        const h2* Up = U + 2*(uoff + p*sn);
        h2 ur = Up[0], ui = Up[1];
        h2 aR = ur * vR[0];
        aR = pkfma(-ui, vI[0], aR);
        h2 aI = ur * vI[0];
        aI = pkfma(ui, vR[0], aI);
        #pragma unroll
        for (int q = 1; q < sn; ++q) {
            ur = Up[2*q]; ui = Up[2*q + 1];
            aR = pkfma(ur, vR[q], aR);
            aR = pkfma(-ui, vI[q], aR);
            aI = pkfma(ur, vI[q], aI);
            aI = pkfma(ui, vR[q], aI);
        }
        oR[p-R0] = aR; oI[p-R0] = aI;
    }
    #pragma unroll
    for (int p = R0; p < R1; ++p) {
        const int c = 5*(imin + p) + n;
        const h2 r = oR[p-R0], m = oI[p-R0];
        psi[base + (c/6)*SA + (c%6)*SB] = (h4){r.x, r.y, m.x, m.y};
    }
}

// BS pass: 4 wave-aligned quarters of 256 threads; whole-block groups (no row
// splits -- those race on read-vs-write of shared block inputs).
// packed-cMAC: q0={5}=36, q1={4,2,1}=38, q2={6,8,9}=38, q3={3,7,0,10}=34.
template<int SA, int SB>
__device__ __forceinline__ void pass_bs(const h2* __restrict__ U,
                                        h4* __restrict__ psi,
                                        const int base, const bool act, const int qid)
{
    if (qid == 0) {
        bs_rows<SA,SB,5,0,6>(U, psi, base, act);
    } else if (qid == 1) {
        bs_rows<SA,SB,4,0,5>(U, psi, base, act);
        bs_rows<SA,SB,2,0,3>(U, psi, base, act);
        bs_rows<SA,SB,1,0,2>(U, psi, base, act);
    } else if (qid == 2) {
        bs_rows<SA,SB,6,0,5>(U, psi, base, act);
        bs_rows<SA,SB,8,0,3>(U, psi, base, act);
        bs_rows<SA,SB,9,0,2>(U, psi, base, act);
    } else {
        bs_rows<SA,SB,3,0,4>(U, psi, base, act);
        bs_rows<SA,SB,7,0,4>(U, psi, base, act);
        bs_rows<SA,SB,0,0,1>(U, psi, base, act);
        bs_rows<SA,SB,10,0,1>(U, psi, base, act);
    }
    __syncthreads();
}

// one single-mode-gate fiber (6 amplitudes, stride SM), 8B-packed
template<int SM, bool SP>
__device__ __forceinline__ void sg_fiber(const h2* __restrict__ G,
                                         h4* __restrict__ psi,
                                         const int base)
{
    h2 vR[6], vI[6];
    #pragma unroll
    for (int k = 0; k < 6; ++k) {
        const h4 v = psi[base + k*SM];
        vR[k] = (h2){v.x, v.y};
        vI[k] = (h2){v.z, v.w};
    }
    h2 oR[6], oI[6];
    #pragma unroll
    for (int o = 0; o < 6; ++o) {
        const int k0 = SP ? (o & 1) : 0;
        const int st = SP ? 2 : 1;
        h2 ur = G[2*(o*6 + k0)], ui = G[2*(o*6 + k0) + 1];
        h2 aR = ur * vR[k0];
        aR = pkfma(-ui, vI[k0], aR);
        h2 aI = ur * vI[k0];
        aI = pkfma(ui, vR[k0], aI);
        #pragma unroll
        for (int k = k0 + st; k < 6; k += st) {
            ur = G[2*(o*6 + k)]; ui = G[2*(o*6 + k) + 1];
            aR = pkfma(ur, vR[k], aR);
            aR = pkfma(-ui, vI[k], aR);
            aI = pkfma(ur, vI[k], aI);
            aI = pkfma(ui, vR[k], aI);
        }
        oR[o] = aR; oI[o] = aI;
    }
    #pragma unroll
    for (int o = 0; o < 6; ++o)
        psi[base + o*SM] = (h4){oR[o].x, oR[o].y, oI[o].x, oI[o].y};
}

// single-mode gate pass: 1296 fibers over 1024 threads (ragged second round).
// S0..S3 are the spectator strides matched to digit order d0(fast)..d3(slow);
// per-pass ordering is chosen for bank-pair residue balance (see header).
template<int SM, int S0, int S1, int S2, int S3, bool SP>
__device__ __forceinline__ void pass_sg(const h2* __restrict__ G,
                                        h4* __restrict__ psi,
                                        const int4 dg0, const int4 dg1, const bool act1)
{
    {
        const int base = dg0.x*S0 + dg0.y*S1 + dg0.z*S2 + dg0.w*S3;
        sg_fiber<SM,SP>(G, psi, base);
    }
    if (act1) {
        const int base = dg1.x*S0 + dg1.y*S1 + dg1.z*S2 + dg1.w*S3;
        sg_fiber<SM,SP>(G, psi, base);
    }
    __syncthreads();
}

__global__ __launch_bounds__(1024, 8)
void qnet_kernel(const h2* __restrict__ bs,
                 const h2* __restrict__ sg,
                 const float* __restrict__ dcol,
                 float* __restrict__ out,
                 const int B)
{
    // addr = 6*i0 + i1 + 36*i2 + 221*i3 + 1332*i4 (max 7980), 8B per amplitude
    __shared__ __align__(16) h4 psi[7984];      // 63,872 B
    __shared__ float stf[60];
    __shared__ float red[64];

    const int tid = threadIdx.x;
    const int b   = blockIdx.x;          // batch pair (2b, 2b+1)

    const int lim = B * 30;
    if (tid < 60) stf[tid] = (b*60 + tid < lim) ? dcol[b*60 + tid] : 0.f;
    __syncthreads();
    for (int e = tid; e < 7776; e += 1024) {
        int t = e;
        const int i4 = t % 6; t /= 6;
        const int i3 = t % 6; t /= 6;
        const int i2 = t % 6; t /= 6;
        const int i1 = t % 6; t /= 6;
        const int i0 = t;
        const int addr = 6*i0 + i1 + 36*i2 + 221*i3 + 1332*i4;
        const float v0 = stf[i0]*stf[6+i1]*stf[12+i2]*stf[18+i3]*stf[24+i4];
        const float v1 = stf[30+i0]*stf[36+i1]*stf[42+i2]*stf[48+i3]*stf[54+i4];
        psi[addr] = (h4){(_Float16)v0, (_Float16)v1, (_Float16)0.f, (_Float16)0.f};
    }
    __syncthreads();

    // BS mapping: 4 quarters of 256; sub<216 active; fiber f = sub.
    // Digit roles per pass chosen so the fastest lane digit carries the odd
    // stride 221 where possible (bank-pair residue balance for b64).
    const int sub = tid & 255;
    const int qid = __builtin_amdgcn_readfirstlane(tid >> 8);   // wave-uniform
    const bool act = sub < 216;
    const int f = act ? sub : 215;
    const int fa = f / 36, rem = f - fa*36;
    const int fb = rem / 6, fc = rem - fb*6;
    const int baseK0 = fa*36 + fc*221 + fb*1332;   // pair (0,1): spect i2=fa, i3=fc, i4=fb
    const int baseK1 = fb*6  + fc*221 + fa*1332;   // pair (1,2): spect i0=fb, i3=fc, i4=fa
    const int baseK2 = rem   + fa*1332;            // pair (2,3): spect i0=fb,i1=fc (contig), i4=fa
    const int baseK3 = f;                          // pair (3,4): spect i2=fa, i0=fb, i1=fc (contig)

    // SG mapping: fibers tid and tid+1024 (<1296); digits precomputed once
    int4 dg0, dg1;
    { int t = tid;        dg0.x = t % 6; t /= 6; dg0.y = t % 6; t /= 6; dg0.z = t % 6; dg0.w = t / 6; }
    { int t = tid + 1024; dg1.x = t % 6; t /= 6; dg1.y = t % 6; t /= 6; dg1.z = t % 6; dg1.w = t / 6; }
    const bool act1 = tid < 272;

    for (int l = 0; l < 4; ++l) {
        const h2* bsl = bs + l * 20 * 292;
        const h2* sgl = sg + l * 10 * 72;
        for (int hf = 0; hf < 2; ++hf) {
            const h2* bh = bsl + hf * 10 * 292;
            const h2* sh = sgl + hf * 5 * 72;
            // tail skip: in the final half-layer, gates acting only on modes
            // {2,3,4} commute with the X0/X1 measurement -> drop them.
            const bool last = (l == 3) && (hf == 1);
            // rail order k = {0,2,1,3,0,2,1,3,0,2}
            pass_bs<6,1>      (bh + 0*292, psi, baseK0, act, qid);
            pass_bs<36,221>   (bh + 1*292, psi, baseK2, act, qid);
            pass_bs<1,36>     (bh + 2*292, psi, baseK1, act, qid);
            pass_bs<221,1332> (bh + 3*292, psi, baseK3, act, qid);
            pass_bs<6,1>      (bh + 4*292, psi, baseK0, act, qid);
            pass_bs<36,221>   (bh + 5*292, psi, baseK2, act, qid);
            pass_bs<1,36>     (bh + 6*292, psi, baseK1, act, qid);
            if (!last)
                pass_bs<221,1332> (bh + 7*292, psi, baseK3, act, qid);
            pass_bs<6,1>      (bh + 8*292, psi, baseK0, act, qid);
            if (!last)
                pass_bs<36,221>   (bh + 9*292, psi, baseK2, act, qid);
            if (hf == 0) {   // squeeze gates: parity-sparse
                pass_sg<6,    1,221,36,1332, true>(sh + 0*72, psi, dg0, dg1, act1);
                pass_sg<1,    221,6,36,1332, true>(sh + 1*72, psi, dg0, dg1, act1);
                pass_sg<36,   1,6,221,1332,  true>(sh + 2*72, psi, dg0, dg1, act1);
                pass_sg<221,  1,6,36,1332,   true>(sh + 3*72, psi, dg0, dg1, act1);
                pass_sg<1332, 1,6,36,221,    true>(sh + 4*72, psi, dg0, dg1, act1);
            } else {         // displacement gates: dense
                pass_sg<6,    1,221,36,1332, false>(sh + 0*72, psi, dg0, dg1, act1);
                pass_sg<1,    221,6,36,1332, false>(sh + 1*72, psi, dg0, dg1, act1);
                if (!last) {
                    pass_sg<36,   1,6,221,1332,  false>(sh + 2*72, psi, dg0, dg1, act1);
                    pass_sg<221,  1,6,36,1332,   false>(sh + 3*72, psi, dg0, dg1, act1);
                    pass_sg<1332, 1,6,36,221,    false>(sh + 4*72, psi, dg0, dg1, act1);
                }
            }
        }
    }

    // <psi| X psi> on modes 0 (stride 6) and 1 (stride 1); per-batch f32 accum
    float s0a = 0.f, s0b = 0.f, s1a = 0.f, s1b = 0.f;
    for (int fr = tid; fr < 1296; fr += 1024) {
        const int q0 = fr % 6;
        const int q1 = (fr / 6) % 6;
        const int q2 = (fr / 36) % 6;
        const int q3 = fr / 216;
        const int base0 = q0*1 + q1*36 + q2*221 + q3*1332;   // spectators of mode 0
        #pragma unroll
        for (int j = 0; j < 5; ++j) {
            const h4 a = psi[base0 + 6*j];
            const h4 c = psi[base0 + 6*(j+1)];
            const float w = sqrtf((float)(j+1));
            s0a = fmaf(w, fmaf((float)a.z, (float)c.z, (float)a.x*(float)c.x), s0a);
            s0b = fmaf(w, fmaf((float)a.w, (float)c.w, (float)a.y*(float)c.y), s0b);
        }
        const int base1 = q0*6 + q1*36 + q2*221 + q3*1332;   // spectators of mode 1
        #pragma unroll
        for (int j = 0; j < 5; ++j) {
            const h4 a = psi[base1 + j];
            const h4 c = psi[base1 + j + 1];
            const float w = sqrtf((float)(j+1));
            s1a = fmaf(w, fmaf((float)a.z, (float)c.z, (float)a.x*(float)c.x), s1a);
            s1b = fmaf(w, fmaf((float)a.w, (float)c.w, (float)a.y*(float)c.y), s1b);
        }
    }
    #pragma unroll
    for (int off = 32; off > 0; off >>= 1) {
        s0a += __shfl_down(s0a, off, 64);
        s0b += __shfl_down(s0b, off, 64);
        s1a += __shfl_down(s1a, off, 64);
        s1b += __shfl_down(s1b, off, 64);
    }
    if ((tid & 63) == 0) {
        const int w = tid >> 6;
        red[w*4 + 0] = s0a; red[w*4 + 1] = s1a;
        red[w*4 + 2] = s0b; red[w*4 + 3] = s1b;
    }
    __syncthreads();
    if (tid == 0) {
        float r0 = 0.f, r1 = 0.f, r2 = 0.f, r3 = 0.f;
        #pragma unroll
        for (int w = 0; w < 16; ++w) {
            r0 += red[w*4 + 0]; r1 += red[w*4 + 1];
            r2 += red[w*4 + 2]; r3 += red[w*4 + 3];
        }
        const int b0 = 2*b, b1 = 2*b + 1;
        out[b0*2 + 0] = 2.f * r0;
        out[b0*2 + 1] = 2.f * r1;
        if (b1 < B) {
            out[b1*2 + 0] = 2.f * r2;
            out[b1*2 + 1] = 2.f * r3;
        }
    }
}

// ---------------------------------------------------------------------------
extern "C" void kernel_launch(void* const* d_in, const int* in_sizes, int n_in,
                              void* d_out, int out_size, void* d_ws, size_t ws_size,
                              hipStream_t stream)
{
    const float* x    = (const float*)d_in[0];   // (B, 5)
    const float* lin  = (const float*)d_in[1];   // (4, 63)
    const float* act  = (const float*)d_in[2];   // (3, 5)
    const float* lact = (const float*)d_in[3];   // (5,)
    float* out = (float*)d_out;                  // (B, 2) float32

    const int B = in_sizes[0] / 5;

    // ws layout: 80 BS gates (292 h2) | 40 single gates (72 h2) | dcol f32
    h2*    bsh = (h2*)d_ws;
    h2*    sgh = bsh + 80*292;
    float* dc  = (float*)(sgh + 40*72);

    gates_kernel<<<dim3(81), dim3(256), 0, stream>>>(lin, act, lact, bsh, sgh);
    const int total = B * 5;
    dcol_kernel<<<dim3((total + 255)/256), dim3(256), 0, stream>>>(x, dc, total);
    qnet_kernel<<<dim3((B + 1) / 2), dim3(1024), 0, stream>>>(bsh, sgh, dc, out, B);
}

// Round 5
// 782.086 us; speedup vs baseline: 1.0631x; 1.0028x over previous
//
#include <hip/hip_runtime.h>

// QuantumDenseNet R17: R14 layout restored + tail commute-skip kept.
// R16 post-mortem: the bank-pair residue remap was refuted -- SQ_LDS_BANK_CONFLICT
// is dominated by the intrinsic 4-phase aliasing of ds_*_b64 (~2 counted cycles
// per wave-op), which layout tuning cannot remove. The remap was ~1.5% net cost.
// This round: exact R14 strides {6,1,36,221,1334} + digit maps (673us verified)
// with R15/R16's verified tail skip (final half-layer gates on modes {2,3,4}
// commute with the X0/X1 measurement: BS passes 7,9 + Dp on modes 2,3,4).

typedef float    vf2 __attribute__((ext_vector_type(2)));
typedef _Float16 h2  __attribute__((ext_vector_type(2)));
typedef _Float16 h4  __attribute__((ext_vector_type(4)));

__device__ __forceinline__ h2 pkfma(const h2 a, const h2 b, const h2 c) {
    return __builtin_elementwise_fma(a, b, c);
}

__device__ __forceinline__ void cmadd(float &ax, float &ay, const float2 u, const float2 v) {
    ax = fmaf(u.x, v.x, ax);
    ax = fmaf(-u.y, v.y, ax);
    ay = fmaf(u.x, v.y, ay);
    ay = fmaf(u.y, v.x, ay);
}

// block-diagonal structure of the 36x36 BS gate (total photon number n=0..10)
constexpr int BS_SN[11]  = {1,2,3,4,5,6,5,4,3,2,1};
constexpr int BS_OFF[11] = {0,1,5,14,30,55,91,116,132,141,145};
// mode strides (amp units): {6, 1, 36, 221, 1334}; max addr 7990

// runtime-indexed copy for gates_kernel packing
__device__ const int d_BS_OFF[12] = {0,1,5,14,30,55,91,116,132,141,145,146};
__device__ const int d_BS_SN[11]  = {1,2,3,4,5,6,5,4,3,2,1};

// ---------------------------------------------------------------------------
// Gate precompute: blocks 0..79 -> BS gates packed block-diag as BROADCAST h2
// pairs {ur,ur},{ui,ui} (292 h2/gate); block 80 -> 40 single-mode combined
// gates (72 h2/gate), same broadcast packing.
// ---------------------------------------------------------------------------
__global__ void gates_kernel(const float* __restrict__ lin,
                             const float* __restrict__ act,
                             const float* __restrict__ lact,
                             h2* __restrict__ bsh,
                             h2* __restrict__ sgh)
{
    __shared__ float2 B0[1296];
    __shared__ float2 B1[1296];
    const int tid = threadIdx.x;

    if (blockIdx.x < 80) {
        const int g = blockIdx.x;
        const int l = g / 20;
        const int w = g % 20;
        const int q = w / 10;
        const int n = w % 10;
        const float theta = lin[l*63 + (q ? 29 : 0) + n];
        const float phi   = lin[l*63 + (q ? 39 : 10) + n];
        const float ts = theta * 0.015625f;
        const float cp = cosf(phi), sp = sinf(phi);
        const float2 u  = make_float2( ts*cp, ts*sp);
        const float2 w2 = make_float2(-ts*cp, ts*sp);

        float2 *R = B0, *T = B1;
        for (int e = tid; e < 1296; e += 256)
            R[e] = make_float2((e % 37 == 0) ? 1.f : 0.f, 0.f);
        __syncthreads();

        for (int k = 16; k >= 1; --k) {
            const float invk = 1.f / (float)k;
            for (int e = tid; e < 1296; e += 256) {
                const int row = e / 36, c = e - row*36;
                const int i = row / 6, j = row - (row/6)*6;
                float ax = 0.f, ay = 0.f;
                if (i < 5 && j > 0) {
                    const float coef = sqrtf((float)((i+1)*j));
                    const float2 x = R[(row+5)*36 + c];
                    const float px = u.x*x.x - u.y*x.y;
                    const float py = u.x*x.y + u.y*x.x;
                    ax = fmaf(coef, px, ax); ay = fmaf(coef, py, ay);
                }
                if (i > 0 && j < 5) {
                    const float coef = sqrtf((float)(i*(j+1)));
                    const float2 x = R[(row-5)*36 + c];
                    const float px = w2.x*x.x - w2.y*x.y;
                    const float py = w2.x*x.y + w2.y*x.x;
                    ax = fmaf(coef, px, ax); ay = fmaf(coef, py, ay);
                }
                T[e] = make_float2(((row == c) ? 1.f : 0.f) + ax*invk, ay*invk);
            }
            __syncthreads();
            float2* tmp = R; R = T; T = tmp;
        }
        for (int s2 = 0; s2 < 6; ++s2) {
            for (int e = tid; e < 1296; e += 256) {
                const int row = e / 36, c = e - row*36;
                float ax = 0.f, ay = 0.f;
                #pragma unroll 6
                for (int k = 0; k < 36; ++k)
                    cmadd(ax, ay, R[row*36 + k], R[k*36 + c]);
                T[e] = make_float2(ax, ay);
            }
            __syncthreads();
            float2* tmp = R; R = T; T = tmp;
        }
        for (int idx = tid; idx < 146; idx += 256) {
            int nn = 0;
            while (idx >= d_BS_OFF[nn+1]) ++nn;
            const int sn  = d_BS_SN[nn];
            const int rel = idx - d_BS_OFF[nn];
            const int p = rel / sn, qq = rel % sn;
            const int imin = (nn > 5) ? (nn - 5) : 0;
            const int row = 5*(imin + p)  + nn;
            const int col = 5*(imin + qq) + nn;
            const float2 z = R[row*36 + col];
            bsh[g*292 + 2*idx    ] = (h2){(_Float16)z.x, (_Float16)z.x};
            bsh[g*292 + 2*idx + 1] = (h2){(_Float16)z.y, (_Float16)z.y};
        }
    } else {
        const int t = tid;
        if (t >= 40) return;
        const int l  = t / 10;
        const int gi = t % 10;
        float2 G[36];
        if (gi < 5) {
            // Sq[m] = squeeze(r) @ diag(e^{i rphi1 * n})  (parity-banded)
            const int m = gi;
            const float r    = lin[l*63 + 24 + m];
            const float rphi = (m < 4) ? lin[l*63 + 20 + m] : 0.f;
            float R[36], T[36];
            #pragma unroll
            for (int e = 0; e < 36; ++e) R[e] = (e % 7 == 0) ? 1.f : 0.f;
            float hp[4];
            #pragma unroll
            for (int i = 0; i < 4; ++i)
                hp[i] = 0.5f * r * sqrtf((float)((i+1)*(i+2))) * 0.015625f;
            for (int k = 16; k >= 1; --k) {
                const float invk = 1.f / (float)k;
                #pragma unroll
                for (int i = 0; i < 6; ++i) {
                    #pragma unroll
                    for (int c = 0; c < 6; ++c) {
                        float a = 0.f;
                        if (i < 4)  a = fmaf( hp[i],   R[(i+2)*6 + c], a);
                        if (i >= 2) a = fmaf(-hp[i-2], R[(i-2)*6 + c], a);
                        T[i*6+c] = ((i == c) ? 1.f : 0.f) + a*invk;
                    }
                }
                #pragma unroll
                for (int e = 0; e < 36; ++e) R[e] = T[e];
            }
            for (int s2 = 0; s2 < 6; ++s2) {
                #pragma unroll
                for (int i = 0; i < 6; ++i) {
                    #pragma unroll
                    for (int c = 0; c < 6; ++c) {
                        float a = 0.f;
                        #pragma unroll
                        for (int k = 0; k < 6; ++k) a = fmaf(R[i*6+k], R[k*6+c], a);
                        T[i*6+c] = a;
                    }
                }
                #pragma unroll
                for (int e = 0; e < 36; ++e) R[e] = T[e];
            }
            #pragma unroll
            for (int c = 0; c < 6; ++c) {
                const float cc = cosf(rphi * (float)c), ss = sinf(rphi * (float)c);
                #pragma unroll
                for (int o = 0; o < 6; ++o)
                    G[o*6 + c] = make_float2(R[o*6+c]*cc, R[o*6+c]*ss);
            }
        } else {
            // Dp[m] = diag(e^{i kap n^2}) @ disp(dr,dp) @ diag(e^{i rphi2 n})
            const int m = gi - 5;
            const float dr   = lin[l*63 + 53 + m];
            const float dp   = lin[l*63 + 58 + m];
            const float rphi = (m < 4) ? lin[l*63 + 49 + m] : 0.f;
            const float kap  = (l < 3) ? act[l*5 + m] : ((m < 2) ? lact[m] : 0.f);
            const float2 al = make_float2(dr * cosf(dp), dr * sinf(dp));
            float2 R[36], T[36];
            #pragma unroll
            for (int e = 0; e < 36; ++e)
                R[e] = make_float2((e % 7 == 0) ? 1.f : 0.f, 0.f);
            float2 cm[6], cpb[6];
            #pragma unroll
            for (int i = 0; i < 6; ++i) {
                const float sm  = sqrtf((float)i)     * 0.015625f;
                const float sp2 = sqrtf((float)(i+1)) * 0.015625f;
                cm[i]  = make_float2( al.x*sm,  al.y*sm);
                cpb[i] = make_float2(-al.x*sp2, al.y*sp2);
            }
            for (int k = 16; k >= 1; --k) {
                const float invk = 1.f / (float)k;
                #pragma unroll
                for (int i = 0; i < 6; ++i) {
                    #pragma unroll
                    for (int c = 0; c < 6; ++c) {
                        float ax = 0.f, ay = 0.f;
                        if (i >= 1) cmadd(ax, ay, cm[i],  R[(i-1)*6 + c]);
                        if (i < 5)  cmadd(ax, ay, cpb[i], R[(i+1)*6 + c]);
                        T[i*6+c] = make_float2(((i == c) ? 1.f : 0.f) + ax*invk, ay*invk);
                    }
                }
                #pragma unroll
                for (int e = 0; e < 36; ++e) R[e] = T[e];
            }
            for (int s2 = 0; s2 < 6; ++s2) {
                #pragma unroll
                for (int i = 0; i < 6; ++i) {
                    #pragma unroll
                    for (int c = 0; c < 6; ++c) {
                        float ax = 0.f, ay = 0.f;
                        #pragma unroll
                        for (int k = 0; k < 6; ++k) cmadd(ax, ay, R[i*6+k], R[k*6+c]);
                        T[i*6+c] = make_float2(ax, ay);
                    }
                }
                #pragma unroll
                for (int e = 0; e < 36; ++e) R[e] = T[e];
            }
            #pragma unroll
            for (int o = 0; o < 6; ++o) {
                const float ko = kap * (float)(o*o);
                const float2 kp = make_float2(cosf(ko), sinf(ko));
                #pragma unroll
                for (int c = 0; c < 6; ++c) {
                    const float rc = rphi * (float)c;
                    const float2 rp = make_float2(cosf(rc), sinf(rc));
                    const float2 z = R[o*6 + c];
                    const float2 t1 = make_float2(kp.x*z.x - kp.y*z.y, kp.x*z.y + kp.y*z.x);
                    G[o*6 + c] = make_float2(t1.x*rp.x - t1.y*rp.y, t1.x*rp.y + t1.y*rp.x);
                }
            }
        }
        h2* outp = sgh + (l*10 + gi)*72;
        #pragma unroll
        for (int e = 0; e < 36; ++e) {
            outp[2*e    ] = (h2){(_Float16)G[e].x, (_Float16)G[e].x};
            outp[2*e + 1] = (h2){(_Float16)G[e].y, (_Float16)G[e].y};
        }
    }
}

// ---------------------------------------------------------------------------
// Initial displacement (phi=0 -> real expm): column 0 per (batch, mode).
// ---------------------------------------------------------------------------
__global__ void dcol_kernel(const float* __restrict__ x,
                            float* __restrict__ dcol, const int total)
{
    const int i = blockIdx.x * 256 + threadIdx.x;
    if (i >= total) return;
    const float xv = x[i];
    float a[5];
    #pragma unroll
    for (int j = 0; j < 5; ++j) a[j] = xv * sqrtf((float)(j+1)) * 0.015625f;
    float R[36], T[36];
    #pragma unroll
    for (int e = 0; e < 36; ++e) R[e] = (e % 7 == 0) ? 1.f : 0.f;
    for (int k = 16; k >= 1; --k) {
        const float invk = 1.f / (float)k;
        #pragma unroll
        for (int r = 0; r < 6; ++r) {
            #pragma unroll
            for (int c = 0; c < 6; ++c) {
                float acc = 0.f;
                if (r >= 1) acc = fmaf( a[r-1], R[(r-1)*6 + c], acc);
                if (r < 5)  acc = fmaf(-a[r],   R[(r+1)*6 + c], acc);
                T[r*6+c] = ((r == c) ? 1.f : 0.f) + acc*invk;
            }
        }
        #pragma unroll
        for (int e = 0; e < 36; ++e) R[e] = T[e];
    }
    for (int s2 = 0; s2 < 6; ++s2) {
        #pragma unroll
        for (int r = 0; r < 6; ++r) {
            #pragma unroll
            for (int c = 0; c < 6; ++c) {
                float acc = 0.f;
                #pragma unroll
                for (int k = 0; k < 6; ++k) acc = fmaf(R[r*6+k], R[k*6+c], acc);
                T[r*6+c] = acc;
            }
        }
        #pragma unroll
        for (int e = 0; e < 36; ++e) R[e] = T[e];
    }
    #pragma unroll
    for (int j = 0; j < 6; ++j) dcol[i*6 + j] = R[j*6 + 0];
}

// ---------------------------------------------------------------------------
// Main kernel building blocks (batch-pair packed, 8B complex amplitudes)
// ---------------------------------------------------------------------------

// rows [R0,R1) of photon block n of one BS pass. One ds_read_b64 per input
// amplitude; lo h2 = re{b0,b1}, hi h2 = im{b0,b1}. Broadcast gates:
//   aR += ur*vR - ui*vI ; aI += ur*vI + ui*vR
template<int SA, int SB, int n, int R0, int R1>
__device__ __forceinline__ void bs_rows(const h2* __restrict__ U,
                                        h4* __restrict__ psi,
                                        const int base, const bool act)
{
    constexpr int sn = BS_SN[n], uoff = BS_OFF[n];
    constexpr int imin = (n > 5) ? (n - 5) : 0;
    if (!act) return;
    h2 vR[sn], vI[sn];
    #pragma unroll
    for (int q = 0; q < sn; ++q) {
        const int c = 5*(imin + q) + n;
        const h4 v = psi[base + (c/6)*SA + (c%6)*SB];
        vR[q] = (h2){v.x, v.y};
        vI[q] = (h2){v.z, v.w};
    }
    h2 oR[R1-R0], oI[R1-R0];
    #pragma unroll
    for (int p = R0; p < R1; ++p) {
        const h2* Up = U + 2*(uoff + p*sn);
        h2 ur = Up[0], ui = Up[1];
        h2 aR = ur * vR[0];
        aR = pkfma(-ui, vI[0], aR);
        h2 aI = ur * vI[0];
        aI = pkfma(ui, vR[0], aI);
        #pragma unroll
        for (int q = 1; q < sn; ++q) {
            ur = Up[2*q]; ui = Up[2*q + 1];
            aR = pkfma(ur, vR[q], aR);
            aR = pkfma(-ui, vI[q], aR);
            aI = pkfma(ur, vI[q], aI);
            aI = pkfma(ui, vR[q], aI);
        }
        oR[p-R0] = aR; oI[p-R0] = aI;
    }
    #pragma unroll
    for (int p = R0; p < R1; ++p) {
        const int c = 5*(imin + p) + n;
        const h2 r = oR[p-R0], m = oI[p-R0];
        psi[base + (c/6)*SA + (c%6)*SB] = (h4){r.x, r.y, m.x, m.y};
    }
}

// BS pass: 4 wave-aligned quarters of 256 threads; whole-block groups (no row
// splits -- those race on read-vs-write of shared block inputs).
// packed-cMAC: q0={5}=36, q1={4,2,1}=38, q2={6,8,9}=38, q3={3,7,0,10}=34.
// (max quarter = 38 is optimal for any whole-block partition.)
template<int SA, int SB>
__device__ __forceinline__ void pass_bs(const h2* __restrict__ U,
                                        h4* __restrict__ psi,
                                        const int base, const bool act, const int qid)
{
    if (qid == 0) {
        bs_rows<SA,SB,5,0,6>(U, psi, base, act);
    } else if (qid == 1) {
        bs_rows<SA,SB,4,0,5>(U, psi, base, act);
        bs_rows<SA,SB,2,0,3>(U, psi, base, act);
        bs_rows<SA,SB,1,0,2>(U, psi, base, act);
    } else if (qid == 2) {
        bs_rows<SA,SB,6,0,5>(U, psi, base, act);
        bs_rows<SA,SB,8,0,3>(U, psi, base, act);
        bs_rows<SA,SB,9,0,2>(U, psi, base, act);
    } else {
        bs_rows<SA,SB,3,0,4>(U, psi, base, act);
        bs_rows<SA,SB,7,0,4>(U, psi, base, act);
        bs_rows<SA,SB,0,0,1>(U, psi, base, act);
        bs_rows<SA,SB,10,0,1>(U, psi, base, act);
    }
    __syncthreads();
}

// one single-mode-gate fiber (6 amplitudes, stride SM), 8B-packed
template<int SM, bool SP>
__device__ __forceinline__ void sg_fiber(const h2* __restrict__ G,
                                         h4* __restrict__ psi,
                                         const int base)
{
    h2 vR[6], vI[6];
    #pragma unroll
    for (int k = 0; k < 6; ++k) {
        const h4 v = psi[base + k*SM];
        vR[k] = (h2){v.x, v.y};
        vI[k] = (h2){v.z, v.w};
    }
    h2 oR[6], oI[6];
    #pragma unroll
    for (int o = 0; o < 6; ++o) {
        const int k0 = SP ? (o & 1) : 0;
        const int st = SP ? 2 : 1;
        h2 ur = G[2*(o*6 + k0)], ui = G[2*(o*6 + k0) + 1];
        h2 aR = ur * vR[k0];
        aR = pkfma(-ui, vI[k0], aR);
        h2 aI = ur * vI[k0];
        aI = pkfma(ui, vR[k0], aI);
        #pragma unroll
        for (int k = k0 + st; k < 6; k += st) {
            ur = G[2*(o*6 + k)]; ui = G[2*(o*6 + k) + 1];
            aR = pkfma(ur, vR[k], aR);
            aR = pkfma(-ui, vI[k], aR);
            aI = pkfma(ur, vI[k], aI);
            aI = pkfma(ui, vR[k], aI);
        }
        oR[o] = aR; oI[o] = aI;
    }
    #pragma unroll
    for (int o = 0; o < 6; ++o)
        psi[base + o*SM] = (h4){oR[o].x, oR[o].y, oI[o].x, oI[o].y};
}

// single-mode gate pass: 1296 fibers over 1024 threads (ragged second round).
// dg0/dg1 = precomputed base-6 digits of fiber ids tid and tid+1024.
template<int SM, int S0, int S1, int S2, int S3, bool SP>
__device__ __forceinline__ void pass_sg(const h2* __restrict__ G,
                                        h4* __restrict__ psi,
                                        const int4 dg0, const int4 dg1, const bool act1)
{
    {
        const int base = dg0.x*S0 + dg0.y*S1 + dg0.z*S2 + dg0.w*S3;
        sg_fiber<SM,SP>(G, psi, base);
    }
    if (act1) {
        const int base = dg1.x*S0 + dg1.y*S1 + dg1.z*S2 + dg1.w*S3;
        sg_fiber<SM,SP>(G, psi, base);
    }
    __syncthreads();
}

__global__ __launch_bounds__(1024, 8)
void qnet_kernel(const h2* __restrict__ bs,
                 const h2* __restrict__ sg,
                 const float* __restrict__ dcol,
                 float* __restrict__ out,
                 const int B)
{
    // addr = 6*i0 + i1 + 36*i2 + 221*i3 + 1334*i4 (max 7990), 8B per amplitude
    __shared__ __align__(16) h4 psi[7992];      // 63,936 B
    __shared__ float stf[60];
    __shared__ float red[64];

    const int tid = threadIdx.x;
    const int b   = blockIdx.x;          // batch pair (2b, 2b+1)

    const int lim = B * 30;
    if (tid < 60) stf[tid] = (b*60 + tid < lim) ? dcol[b*60 + tid] : 0.f;
    __syncthreads();
    for (int e = tid; e < 7776; e += 1024) {
        int t = e;
        const int i4 = t % 6; t /= 6;
        const int i3 = t % 6; t /= 6;
        const int i2 = t % 6; t /= 6;
        const int i1 = t % 6; t /= 6;
        const int i0 = t;
        const int addr = 6*i0 + i1 + 36*i2 + 221*i3 + 1334*i4;
        const float v0 = stf[i0]*stf[6+i1]*stf[12+i2]*stf[18+i3]*stf[24+i4];
        const float v1 = stf[30+i0]*stf[36+i1]*stf[42+i2]*stf[48+i3]*stf[54+i4];
        psi[addr] = (h4){(_Float16)v0, (_Float16)v1, (_Float16)0.f, (_Float16)0.f};
    }
    __syncthreads();

    // BS mapping: 4 quarters of 256; sub<216 active; fiber f = sub
    const int sub = tid & 255;
    const int qid = __builtin_amdgcn_readfirstlane(tid >> 8);   // wave-uniform
    const bool act = sub < 216;
    const int f = act ? sub : 215;
    const int fa = f / 36, rem = f - fa*36;
    const int fb = rem / 6, fc = rem - fb*6;
    const int baseK0 = fa*36 + fb*221 + fc*1334;   // pair (0,1): spect 2,3,4
    const int baseK1 = fa*6  + fb*221 + fc*1334;   // pair (1,2): spect 0,3,4
    const int baseK2 = rem   + fa*1334;            // pair (2,3): spect 0,1 (contig), 4
    const int baseK3 = f;                          // pair (3,4): spect 0,1,2 (contig)

    // SG mapping: fibers tid and tid+1024 (<1296); digits precomputed once
    int4 dg0, dg1;
    { int t = tid;        dg0.x = t % 6; t /= 6; dg0.y = t % 6; t /= 6; dg0.z = t % 6; dg0.w = t / 6; }
    { int t = tid + 1024; dg1.x = t % 6; t /= 6; dg1.y = t % 6; t /= 6; dg1.z = t % 6; dg1.w = t / 6; }
    const bool act1 = tid < 272;

    for (int l = 0; l < 4; ++l) {
        const h2* bsl = bs + l * 20 * 292;
        const h2* sgl = sg + l * 10 * 72;
        for (int hf = 0; hf < 2; ++hf) {
            const h2* bh = bsl + hf * 10 * 292;
            const h2* sh = sgl + hf * 5 * 72;
            // tail skip: in the final half-layer, gates acting only on modes
            // {2,3,4} commute with the X0/X1 measurement -> drop them.
            const bool last = (l == 3) && (hf == 1);
            // rail order k = {0,2,1,3,0,2,1,3,0,2}
            pass_bs<6,1>     (bh + 0*292, psi, baseK0, act, qid);
            pass_bs<36,221>  (bh + 1*292, psi, baseK2, act, qid);
            pass_bs<1,36>    (bh + 2*292, psi, baseK1, act, qid);
            pass_bs<221,1334>(bh + 3*292, psi, baseK3, act, qid);
            pass_bs<6,1>     (bh + 4*292, psi, baseK0, act, qid);
            pass_bs<36,221>  (bh + 5*292, psi, baseK2, act, qid);
            pass_bs<1,36>    (bh + 6*292, psi, baseK1, act, qid);
            if (!last)
                pass_bs<221,1334>(bh + 7*292, psi, baseK3, act, qid);
            pass_bs<6,1>     (bh + 8*292, psi, baseK0, act, qid);
            if (!last)
                pass_bs<36,221>  (bh + 9*292, psi, baseK2, act, qid);
            if (hf == 0) {   // squeeze gates: parity-sparse
                pass_sg<6,    1,36,221,1334, true>(sh + 0*72, psi, dg0, dg1, act1);
                pass_sg<1,    6,36,221,1334, true>(sh + 1*72, psi, dg0, dg1, act1);
                pass_sg<36,   1,6,221,1334,  true>(sh + 2*72, psi, dg0, dg1, act1);
                pass_sg<221,  1,6,36,1334,   true>(sh + 3*72, psi, dg0, dg1, act1);
                pass_sg<1334, 1,6,36,221,    true>(sh + 4*72, psi, dg0, dg1, act1);
            } else {         // displacement gates: dense
                pass_sg<6,    1,36,221,1334, false>(sh + 0*72, psi, dg0, dg1, act1);
                pass_sg<1,    6,36,221,1334, false>(sh + 1*72, psi, dg0, dg1, act1);
                if (!last) {
                    pass_sg<36,   1,6,221,1334,  false>(sh + 2*72, psi, dg0, dg1, act1);
                    pass_sg<221,  1,6,36,1334,   false>(sh + 3*72, psi, dg0, dg1, act1);
                    pass_sg<1334, 1,6,36,221,    false>(sh + 4*72, psi, dg0, dg1, act1);
                }
            }
        }
    }

    // <psi| X psi> on modes 0 (stride 6) and 1 (stride 1); per-batch f32 accum
    float s0a = 0.f, s0b = 0.f, s1a = 0.f, s1b = 0.f;
    for (int fr = tid; fr < 1296; fr += 1024) {
        const int q0 = fr % 6;
        const int q1 = (fr / 6) % 6;
        const int q2 = (fr / 36) % 6;
        const int q3 = fr / 216;
        const int base0 = q0*1 + q1*36 + q2*221 + q3*1334;   // spectators of mode 0
        #pragma unroll
        for (int j = 0; j < 5; ++j) {
            const h4 a = psi[base0 + 6*j];
            const h4 c = psi[base0 + 6*(j+1)];
            const float w = sqrtf((float)(j+1));
            s0a = fmaf(w, fmaf((float)a.z, (float)c.z, (float)a.x*(float)c.x), s0a);
            s0b = fmaf(w, fmaf((float)a.w, (float)c.w, (float)a.y*(float)c.y), s0b);
        }
        const int base1 = q0*6 + q1*36 + q2*221 + q3*1334;   // spectators of mode 1
        #pragma unroll
        for (int j = 0; j < 5; ++j) {
            const h4 a = psi[base1 + j];
            const h4 c = psi[base1 + j + 1];
            const float w = sqrtf((float)(j+1));
            s1a = fmaf(w, fmaf((float)a.z, (float)c.z, (float)a.x*(float)c.x), s1a);
            s1b = fmaf(w, fmaf((float)a.w, (float)c.w, (float)a.y*(float)c.y), s1b);
        }
    }
    #pragma unroll
    for (int off = 32; off > 0; off >>= 1) {
        s0a += __shfl_down(s0a, off, 64);
        s0b += __shfl_down(s0b, off, 64);
        s1a += __shfl_down(s1a, off, 64);
        s1b += __shfl_down(s1b, off, 64);
    }
    if ((tid & 63) == 0) {
        const int w = tid >> 6;
        red[w*4 + 0] = s0a; red[w*4 + 1] = s1a;
        red[w*4 + 2] = s0b; red[w*4 + 3] = s1b;
    }
    __syncthreads();
    if (tid == 0) {
        float r0 = 0.f, r1 = 0.f, r2 = 0.f, r3 = 0.f;
        #pragma unroll
        for (int w = 0; w < 16; ++w) {
            r0 += red[w*4 + 0]; r1 += red[w*4 + 1];
            r2 += red[w*4 + 2]; r3 += red[w*4 + 3];
        }
        const int b0 = 2*b, b1 = 2*b + 1;
        out[b0*2 + 0] = 2.f * r0;
        out[b0*2 + 1] = 2.f * r1;
        if (b1 < B) {
            out[b1*2 + 0] = 2.f * r2;
            out[b1*2 + 1] = 2.f * r3;
        }
    }
}

// ---------------------------------------------------------------------------
extern "C" void kernel_launch(void* const* d_in, const int* in_sizes, int n_in,
                              void* d_out, int out_size, void* d_ws, size_t ws_size,
                              hipStream_t stream)
{
    const float* x    = (const float*)d_in[0];   // (B, 5)
    const float* lin  = (const float*)d_in[1];   // (4, 63)
    const float* act  = (const float*)d_in[2];   // (3, 5)
    const float* lact = (const float*)d_in[3];   // (5,)
    float* out = (float*)d_out;                  // (B, 2) float32

    const int B = in_sizes[0] / 5;

    // ws layout: 80 BS gates (292 h2) | 40 single gates (72 h2) | dcol f32
    h2*    bsh = (h2*)d_ws;
    h2*    sgh = bsh + 80*292;
    float* dc  = (float*)(sgh + 40*72);

    gates_kernel<<<dim3(81), dim3(256), 0, stream>>>(lin, act, lact, bsh, sgh);
    const int total = B * 5;
    dcol_kernel<<<dim3((total + 255)/256), dim3(256), 0, stream>>>(x, dc, total);
    qnet_kernel<<<dim3((B + 1) / 2), dim3(1024), 0, stream>>>(bsh, sgh, dc, out, B);
}

// Round 6
// 771.397 us; speedup vs baseline: 1.0778x; 1.0139x over previous
//
#include <hip/hip_runtime.h>

// QuantumDenseNet R18: R17 base (648us) + HEAD PEEL. The initial state is a
// product d0⊗d1⊗d2⊗d3⊗d4, and the first BS passes on disjoint rails preserve
// factorization: pass0 (modes 0,1), pass1 (modes 2,3), pass3 (modes 3,4;
// commutes with pass2 on modes 1,2 so it reorders ahead of it). These three
// 7776-amp LDS passes collapse to tiny f32 matvecs computed in-kernel:
//   psi01 = BS01@(d0⊗d1)  [36]
//   psi23 = BS23@(d2⊗d3)  [36];  f234 = BS34@(psi23⊗d4)  [216]
// then psi init = psi01 ⊗ f234. Same f16 gate values as the skipped passes,
// accumulated in f32 -> accuracy >= before. LDS 69KB, still 2 blocks/CU.
// Tail skip kept (last half-layer gates on modes {2,3,4} commute with X0/X1).

typedef float    vf2 __attribute__((ext_vector_type(2)));
typedef _Float16 h2  __attribute__((ext_vector_type(2)));
typedef _Float16 h4  __attribute__((ext_vector_type(4)));

__device__ __forceinline__ h2 pkfma(const h2 a, const h2 b, const h2 c) {
    return __builtin_elementwise_fma(a, b, c);
}

__device__ __forceinline__ void cmadd(float &ax, float &ay, const float2 u, const float2 v) {
    ax = fmaf(u.x, v.x, ax);
    ax = fmaf(-u.y, v.y, ax);
    ay = fmaf(u.x, v.y, ay);
    ay = fmaf(u.y, v.x, ay);
}

// block-diagonal structure of the 36x36 BS gate (total photon number n=0..10)
constexpr int BS_SN[11]  = {1,2,3,4,5,6,5,4,3,2,1};
constexpr int BS_OFF[11] = {0,1,5,14,30,55,91,116,132,141,145};
// mode strides (amp units): {6, 1, 36, 221, 1334}; max addr 7990

// runtime-indexed copy for gates_kernel packing + in-kernel head peel
__device__ const int d_BS_OFF[12] = {0,1,5,14,30,55,91,116,132,141,145,146};
__device__ const int d_BS_SN[11]  = {1,2,3,4,5,6,5,4,3,2,1};

// ---------------------------------------------------------------------------
// Gate precompute: blocks 0..79 -> BS gates packed block-diag as BROADCAST h2
// pairs {ur,ur},{ui,ui} (292 h2/gate); block 80 -> 40 single-mode combined
// gates (72 h2/gate), same broadcast packing.
// ---------------------------------------------------------------------------
__global__ void gates_kernel(const float* __restrict__ lin,
                             const float* __restrict__ act,
                             const float* __restrict__ lact,
                             h2* __restrict__ bsh,
                             h2* __restrict__ sgh)
{
    __shared__ float2 B0[1296];
    __shared__ float2 B1[1296];
    const int tid = threadIdx.x;

    if (blockIdx.x < 80) {
        const int g = blockIdx.x;
        const int l = g / 20;
        const int w = g % 20;
        const int q = w / 10;
        const int n = w % 10;
        const float theta = lin[l*63 + (q ? 29 : 0) + n];
        const float phi   = lin[l*63 + (q ? 39 : 10) + n];
        const float ts = theta * 0.015625f;
        const float cp = cosf(phi), sp = sinf(phi);
        const float2 u  = make_float2( ts*cp, ts*sp);
        const float2 w2 = make_float2(-ts*cp, ts*sp);

        float2 *R = B0, *T = B1;
        for (int e = tid; e < 1296; e += 256)
            R[e] = make_float2((e % 37 == 0) ? 1.f : 0.f, 0.f);
        __syncthreads();

        for (int k = 16; k >= 1; --k) {
            const float invk = 1.f / (float)k;
            for (int e = tid; e < 1296; e += 256) {
                const int row = e / 36, c = e - row*36;
                const int i = row / 6, j = row - (row/6)*6;
                float ax = 0.f, ay = 0.f;
                if (i < 5 && j > 0) {
                    const float coef = sqrtf((float)((i+1)*j));
                    const float2 x = R[(row+5)*36 + c];
                    const float px = u.x*x.x - u.y*x.y;
                    const float py = u.x*x.y + u.y*x.x;
                    ax = fmaf(coef, px, ax); ay = fmaf(coef, py, ay);
                }
                if (i > 0 && j < 5) {
                    const float coef = sqrtf((float)(i*(j+1)));
                    const float2 x = R[(row-5)*36 + c];
                    const float px = w2.x*x.x - w2.y*x.y;
                    const float py = w2.x*x.y + w2.y*x.x;
                    ax = fmaf(coef, px, ax); ay = fmaf(coef, py, ay);
                }
                T[e] = make_float2(((row == c) ? 1.f : 0.f) + ax*invk, ay*invk);
            }
            __syncthreads();
            float2* tmp = R; R = T; T = tmp;
        }
        for (int s2 = 0; s2 < 6; ++s2) {
            for (int e = tid; e < 1296; e += 256) {
                const int row = e / 36, c = e - row*36;
                float ax = 0.f, ay = 0.f;
                #pragma unroll 6
                for (int k = 0; k < 36; ++k)
                    cmadd(ax, ay, R[row*36 + k], R[k*36 + c]);
                T[e] = make_float2(ax, ay);
            }
            __syncthreads();
            float2* tmp = R; R = T; T = tmp;
        }
        for (int idx = tid; idx < 146; idx += 256) {
            int nn = 0;
            while (idx >= d_BS_OFF[nn+1]) ++nn;
            const int sn  = d_BS_SN[nn];
            const int rel = idx - d_BS_OFF[nn];
            const int p = rel / sn, qq = rel % sn;
            const int imin = (nn > 5) ? (nn - 5) : 0;
            const int row = 5*(imin + p)  + nn;
            const int col = 5*(imin + qq) + nn;
            const float2 z = R[row*36 + col];
            bsh[g*292 + 2*idx    ] = (h2){(_Float16)z.x, (_Float16)z.x};
            bsh[g*292 + 2*idx + 1] = (h2){(_Float16)z.y, (_Float16)z.y};
        }
    } else {
        const int t = tid;
        if (t >= 40) return;
        const int l  = t / 10;
        const int gi = t % 10;
        float2 G[36];
        if (gi < 5) {
            // Sq[m] = squeeze(r) @ diag(e^{i rphi1 * n})  (parity-banded)
            const int m = gi;
            const float r    = lin[l*63 + 24 + m];
            const float rphi = (m < 4) ? lin[l*63 + 20 + m] : 0.f;
            float R[36], T[36];
            #pragma unroll
            for (int e = 0; e < 36; ++e) R[e] = (e % 7 == 0) ? 1.f : 0.f;
            float hp[4];
            #pragma unroll
            for (int i = 0; i < 4; ++i)
                hp[i] = 0.5f * r * sqrtf((float)((i+1)*(i+2))) * 0.015625f;
            for (int k = 16; k >= 1; --k) {
                const float invk = 1.f / (float)k;
                #pragma unroll
                for (int i = 0; i < 6; ++i) {
                    #pragma unroll
                    for (int c = 0; c < 6; ++c) {
                        float a = 0.f;
                        if (i < 4)  a = fmaf( hp[i],   R[(i+2)*6 + c], a);
                        if (i >= 2) a = fmaf(-hp[i-2], R[(i-2)*6 + c], a);
                        T[i*6+c] = ((i == c) ? 1.f : 0.f) + a*invk;
                    }
                }
                #pragma unroll
                for (int e = 0; e < 36; ++e) R[e] = T[e];
            }
            for (int s2 = 0; s2 < 6; ++s2) {
                #pragma unroll
                for (int i = 0; i < 6; ++i) {
                    #pragma unroll
                    for (int c = 0; c < 6; ++c) {
                        float a = 0.f;
                        #pragma unroll
                        for (int k = 0; k < 6; ++k) a = fmaf(R[i*6+k], R[k*6+c], a);
                        T[i*6+c] = a;
                    }
                }
                #pragma unroll
                for (int e = 0; e < 36; ++e) R[e] = T[e];
            }
            #pragma unroll
            for (int c = 0; c < 6; ++c) {
                const float cc = cosf(rphi * (float)c), ss = sinf(rphi * (float)c);
                #pragma unroll
                for (int o = 0; o < 6; ++o)
                    G[o*6 + c] = make_float2(R[o*6+c]*cc, R[o*6+c]*ss);
            }
        } else {
            // Dp[m] = diag(e^{i kap n^2}) @ disp(dr,dp) @ diag(e^{i rphi2 n})
            const int m = gi - 5;
            const float dr   = lin[l*63 + 53 + m];
            const float dp   = lin[l*63 + 58 + m];
            const float rphi = (m < 4) ? lin[l*63 + 49 + m] : 0.f;
            const float kap  = (l < 3) ? act[l*5 + m] : ((m < 2) ? lact[m] : 0.f);
            const float2 al = make_float2(dr * cosf(dp), dr * sinf(dp));
            float2 R[36], T[36];
            #pragma unroll
            for (int e = 0; e < 36; ++e)
                R[e] = make_float2((e % 7 == 0) ? 1.f : 0.f, 0.f);
            float2 cm[6], cpb[6];
            #pragma unroll
            for (int i = 0; i < 6; ++i) {
                const float sm  = sqrtf((float)i)     * 0.015625f;
                const float sp2 = sqrtf((float)(i+1)) * 0.015625f;
                cm[i]  = make_float2( al.x*sm,  al.y*sm);
                cpb[i] = make_float2(-al.x*sp2, al.y*sp2);
            }
            for (int k = 16; k >= 1; --k) {
                const float invk = 1.f / (float)k;
                #pragma unroll
                for (int i = 0; i < 6; ++i) {
                    #pragma unroll
                    for (int c = 0; c < 6; ++c) {
                        float ax = 0.f, ay = 0.f;
                        if (i >= 1) cmadd(ax, ay, cm[i],  R[(i-1)*6 + c]);
                        if (i < 5)  cmadd(ax, ay, cpb[i], R[(i+1)*6 + c]);
                        T[i*6+c] = make_float2(((i == c) ? 1.f : 0.f) + ax*invk, ay*invk);
                    }
                }
                #pragma unroll
                for (int e = 0; e < 36; ++e) R[e] = T[e];
            }
            for (int s2 = 0; s2 < 6; ++s2) {
                #pragma unroll
                for (int i = 0; i < 6; ++i) {
                    #pragma unroll
                    for (int c = 0; c < 6; ++c) {
                        float ax = 0.f, ay = 0.f;
                        #pragma unroll
                        for (int k = 0; k < 6; ++k) cmadd(ax, ay, R[i*6+k], R[k*6+c]);
                        T[i*6+c] = make_float2(ax, ay);
                    }
                }
                #pragma unroll
                for (int e = 0; e < 36; ++e) R[e] = T[e];
            }
            #pragma unroll
            for (int o = 0; o < 6; ++o) {
                const float ko = kap * (float)(o*o);
                const float2 kp = make_float2(cosf(ko), sinf(ko));
                #pragma unroll
                for (int c = 0; c < 6; ++c) {
                    const float rc = rphi * (float)c;
                    const float2 rp = make_float2(cosf(rc), sinf(rc));
                    const float2 z = R[o*6 + c];
                    const float2 t1 = make_float2(kp.x*z.x - kp.y*z.y, kp.x*z.y + kp.y*z.x);
                    G[o*6 + c] = make_float2(t1.x*rp.x - t1.y*rp.y, t1.x*rp.y + t1.y*rp.x);
                }
            }
        }
        h2* outp = sgh + (l*10 + gi)*72;
        #pragma unroll
        for (int e = 0; e < 36; ++e) {
            outp[2*e    ] = (h2){(_Float16)G[e].x, (_Float16)G[e].x};
            outp[2*e + 1] = (h2){(_Float16)G[e].y, (_Float16)G[e].y};
        }
    }
}

// ---------------------------------------------------------------------------
// Initial displacement (phi=0 -> real expm): column 0 per (batch, mode).
// ---------------------------------------------------------------------------
__global__ void dcol_kernel(const float* __restrict__ x,
                            float* __restrict__ dcol, const int total)
{
    const int i = blockIdx.x * 256 + threadIdx.x;
    if (i >= total) return;
    const float xv = x[i];
    float a[5];
    #pragma unroll
    for (int j = 0; j < 5; ++j) a[j] = xv * sqrtf((float)(j+1)) * 0.015625f;
    float R[36], T[36];
    #pragma unroll
    for (int e = 0; e < 36; ++e) R[e] = (e % 7 == 0) ? 1.f : 0.f;
    for (int k = 16; k >= 1; --k) {
        const float invk = 1.f / (float)k;
        #pragma unroll
        for (int r = 0; r < 6; ++r) {
            #pragma unroll
            for (int c = 0; c < 6; ++c) {
                float acc = 0.f;
                if (r >= 1) acc = fmaf( a[r-1], R[(r-1)*6 + c], acc);
                if (r < 5)  acc = fmaf(-a[r],   R[(r+1)*6 + c], acc);
                T[r*6+c] = ((r == c) ? 1.f : 0.f) + acc*invk;
            }
        }
        #pragma unroll
        for (int e = 0; e < 36; ++e) R[e] = T[e];
    }
    for (int s2 = 0; s2 < 6; ++s2) {
        #pragma unroll
        for (int r = 0; r < 6; ++r) {
            #pragma unroll
            for (int c = 0; c < 6; ++c) {
                float acc = 0.f;
                #pragma unroll
                for (int k = 0; k < 6; ++k) acc = fmaf(R[r*6+k], R[k*6+c], acc);
                T[r*6+c] = acc;
            }
        }
        #pragma unroll
        for (int e = 0; e < 36; ++e) R[e] = T[e];
    }
    #pragma unroll
    for (int j = 0; j < 6; ++j) dcol[i*6 + j] = R[j*6 + 0];
}

// ---------------------------------------------------------------------------
// Main kernel building blocks (batch-pair packed, 8B complex amplitudes)
// ---------------------------------------------------------------------------

// rows [R0,R1) of photon block n of one BS pass. One ds_read_b64 per input
// amplitude; lo h2 = re{b0,b1}, hi h2 = im{b0,b1}. Broadcast gates:
//   aR += ur*vR - ui*vI ; aI += ur*vI + ui*vR
template<int SA, int SB, int n, int R0, int R1>
__device__ __forceinline__ void bs_rows(const h2* __restrict__ U,
                                        h4* __restrict__ psi,
                                        const int base, const bool act)
{
    constexpr int sn = BS_SN[n], uoff = BS_OFF[n];
    constexpr int imin = (n > 5) ? (n - 5) : 0;
    if (!act) return;
    h2 vR[sn], vI[sn];
    #pragma unroll
    for (int q = 0; q < sn; ++q) {
        const int c = 5*(imin + q) + n;
        const h4 v = psi[base + (c/6)*SA + (c%6)*SB];
        vR[q] = (h2){v.x, v.y};
        vI[q] = (h2){v.z, v.w};
    }
    h2 oR[R1-R0], oI[R1-R0];
    #pragma unroll
    for (int p = R0; p < R1; ++p) {
        const h2* Up = U + 2*(uoff + p*sn);
        h2 ur = Up[0], ui = Up[1];
        h2 aR = ur * vR[0];
        aR = pkfma(-ui, vI[0], aR);
        h2 aI = ur * vI[0];
        aI = pkfma(ui, vR[0], aI);
        #pragma unroll
        for (int q = 1; q < sn; ++q) {
            ur = Up[2*q]; ui = Up[2*q + 1];
            aR = pkfma(ur, vR[q], aR);
            aR = pkfma(-ui, vI[q], aR);
            aI = pkfma(ur, vI[q], aI);
            aI = pkfma(ui, vR[q], aI);
        }
        oR[p-R0] = aR; oI[p-R0] = aI;
    }
    #pragma unroll
    for (int p = R0; p < R1; ++p) {
        const int c = 5*(imin + p) + n;
        const h2 r = oR[p-R0], m = oI[p-R0];
        psi[base + (c/6)*SA + (c%6)*SB] = (h4){r.x, r.y, m.x, m.y};
    }
}

// BS pass: 4 wave-aligned quarters of 256 threads; whole-block groups (no row
// splits -- those race on read-vs-write of shared block inputs).
// packed-cMAC: q0={5}=36, q1={4,2,1}=38, q2={6,8,9}=38, q3={3,7,0,10}=34.
// (max quarter = 38 is optimal for any whole-block partition.)
template<int SA, int SB>
__device__ __forceinline__ void pass_bs(const h2* __restrict__ U,
                                        h4* __restrict__ psi,
                                        const int base, const bool act, const int qid)
{
    if (qid == 0) {
        bs_rows<SA,SB,5,0,6>(U, psi, base, act);
    } else if (qid == 1) {
        bs_rows<SA,SB,4,0,5>(U, psi, base, act);
        bs_rows<SA,SB,2,0,3>(U, psi, base, act);
        bs_rows<SA,SB,1,0,2>(U, psi, base, act);
    } else if (qid == 2) {
        bs_rows<SA,SB,6,0,5>(U, psi, base, act);
        bs_rows<SA,SB,8,0,3>(U, psi, base, act);
        bs_rows<SA,SB,9,0,2>(U, psi, base, act);
    } else {
        bs_rows<SA,SB,3,0,4>(U, psi, base, act);
        bs_rows<SA,SB,7,0,4>(U, psi, base, act);
        bs_rows<SA,SB,0,0,1>(U, psi, base, act);
        bs_rows<SA,SB,10,0,1>(U, psi, base, act);
    }
    __syncthreads();
}

// one single-mode-gate fiber (6 amplitudes, stride SM), 8B-packed
template<int SM, bool SP>
__device__ __forceinline__ void sg_fiber(const h2* __restrict__ G,
                                         h4* __restrict__ psi,
                                         const int base)
{
    h2 vR[6], vI[6];
    #pragma unroll
    for (int k = 0; k < 6; ++k) {
        const h4 v = psi[base + k*SM];
        vR[k] = (h2){v.x, v.y};
        vI[k] = (h2){v.z, v.w};
    }
    h2 oR[6], oI[6];
    #pragma unroll
    for (int o = 0; o < 6; ++o) {
        const int k0 = SP ? (o & 1) : 0;
        const int st = SP ? 2 : 1;
        h2 ur = G[2*(o*6 + k0)], ui = G[2*(o*6 + k0) + 1];
        h2 aR = ur * vR[k0];
        aR = pkfma(-ui, vI[k0], aR);
        h2 aI = ur * vI[k0];
        aI = pkfma(ui, vR[k0], aI);
        #pragma unroll
        for (int k = k0 + st; k < 6; k += st) {
            ur = G[2*(o*6 + k)]; ui = G[2*(o*6 + k) + 1];
            aR = pkfma(ur, vR[k], aR);
            aR = pkfma(-ui, vI[k], aR);
            aI = pkfma(ur, vI[k], aI);
            aI = pkfma(ui, vR[k], aI);
        }
        oR[o] = aR; oI[o] = aI;
    }
    #pragma unroll
    for (int o = 0; o < 6; ++o)
        psi[base + o*SM] = (h4){oR[o].x, oR[o].y, oI[o].x, oI[o].y};
}

// single-mode gate pass: 1296 fibers over 1024 threads (ragged second round).
// dg0/dg1 = precomputed base-6 digits of fiber ids tid and tid+1024.
template<int SM, int S0, int S1, int S2, int S3, bool SP>
__device__ __forceinline__ void pass_sg(const h2* __restrict__ G,
                                        h4* __restrict__ psi,
                                        const int4 dg0, const int4 dg1, const bool act1)
{
    {
        const int base = dg0.x*S0 + dg0.y*S1 + dg0.z*S2 + dg0.w*S3;
        sg_fiber<SM,SP>(G, psi, base);
    }
    if (act1) {
        const int base = dg1.x*S0 + dg1.y*S1 + dg1.z*S2 + dg1.w*S3;
        sg_fiber<SM,SP>(G, psi, base);
    }
    __syncthreads();
}

__global__ __launch_bounds__(1024, 8)
void qnet_kernel(const h2* __restrict__ bs,
                 const h2* __restrict__ sg,
                 const float* __restrict__ dcol,
                 float* __restrict__ out,
                 const int B)
{
    // addr = 6*i0 + i1 + 36*i2 + 221*i3 + 1334*i4 (max 7990), 8B per amplitude
    __shared__ __align__(16) h4 psi[7992];      // 63,936 B
    __shared__ float stf[60];
    __shared__ float red[64];
    // head-peel staging (f32): psi01/psi23 per batch (36), f234 per batch (216)
    __shared__ float2 ps01[2][36];
    __shared__ float2 ps23[2][36];
    __shared__ float2 f234[2][216];

    const int tid = threadIdx.x;
    const int b   = blockIdx.x;          // batch pair (2b, 2b+1)

    const int lim = B * 30;
    if (tid < 60) stf[tid] = (b*60 + tid < lim) ? dcol[b*60 + tid] : 0.f;
    __syncthreads();

    // ---- head peel round A: psi01 = BS01@(d0⊗d1), psi23 = BS23@(d2⊗d3) ----
    // gates: layer0/hf0 pass0 (rail0) at bs+0*292, pass1 (rail2) at bs+1*292
    if (tid < 144) {
        const int part = tid / 36;       // 0:ps01 b0, 1:ps01 b1, 2:ps23 b0, 3:ps23 b1
        const int idx  = tid - part*36;
        const int p    = part & 1;
        const bool m01 = part < 2;
        const int i = idx / 6, j = idx - (idx/6)*6;
        const int n = i + j;
        const int imin = (n > 5) ? (n - 5) : 0;
        const int sn   = d_BS_SN[n];
        const int prow = i - imin;
        const h2* U = bs + (m01 ? 0 : 1)*292 + 2*(d_BS_OFF[n] + prow*sn);
        const float* dA = stf + p*30 + (m01 ? 0 : 12);
        const float* dB = dA + 6;
        float ar = 0.f, ai = 0.f;
        for (int q = 0; q < sn; ++q) {
            const float ur = (float)U[2*q].x, ui = (float)U[2*q+1].x;
            const float dd = dA[imin+q] * dB[n-imin-q];
            ar = fmaf(ur, dd, ar); ai = fmaf(ui, dd, ai);
        }
        if (m01) ps01[p][idx] = make_float2(ar, ai);
        else     ps23[p][idx] = make_float2(ar, ai);
    }
    __syncthreads();

    // ---- head peel round B: f234 = BS34@(psi23⊗d4) (pass3/rail3 commutes
    //      with pass2/rail1, so it legally reorders ahead of it) ----
    if (tid < 432) {
        const int p  = tid / 216;
        const int r  = tid - p*216;
        const int i2 = r / 36, i34 = r - i2*36;
        const int i3 = i34 / 6, i4 = i34 - i3*6;
        const int n  = i3 + i4;
        const int imin = (n > 5) ? (n - 5) : 0;
        const int sn   = d_BS_SN[n];
        const int prow = i3 - imin;
        const h2* U = bs + 3*292 + 2*(d_BS_OFF[n] + prow*sn);
        const float* d4 = stf + p*30 + 24;
        float ar = 0.f, ai = 0.f;
        for (int q = 0; q < sn; ++q) {
            const float ur = (float)U[2*q].x, ui = (float)U[2*q+1].x;
            const float2 w23 = ps23[p][i2*6 + (imin+q)];
            const float dd = d4[n-imin-q];
            ar = fmaf(dd, ur*w23.x - ui*w23.y, ar);
            ai = fmaf(dd, ur*w23.y + ui*w23.x, ai);
        }
        f234[p][r] = make_float2(ar, ai);
    }
    __syncthreads();

    // ---- init: psi = psi01 ⊗ f234 (complex product, rounded once to f16) ----
    for (int e = tid; e < 7776; e += 1024) {
        int t = e;
        const int i4 = t % 6; t /= 6;
        const int i3 = t % 6; t /= 6;
        const int i2 = t % 6; t /= 6;
        const int i1 = t % 6; t /= 6;
        const int i0 = t;
        const int addr = 6*i0 + i1 + 36*i2 + 221*i3 + 1334*i4;
        const int i01 = i0*6 + i1;
        const int r   = i2*36 + i3*6 + i4;
        const float2 a0 = ps01[0][i01], b0 = f234[0][r];
        const float2 a1 = ps01[1][i01], b1 = f234[1][r];
        const float v0r = a0.x*b0.x - a0.y*b0.y, v0i = a0.x*b0.y + a0.y*b0.x;
        const float v1r = a1.x*b1.x - a1.y*b1.y, v1i = a1.x*b1.y + a1.y*b1.x;
        psi[addr] = (h4){(_Float16)v0r, (_Float16)v1r, (_Float16)v0i, (_Float16)v1i};
    }
    __syncthreads();

    // BS mapping: 4 quarters of 256; sub<216 active; fiber f = sub
    const int sub = tid & 255;
    const int qid = __builtin_amdgcn_readfirstlane(tid >> 8);   // wave-uniform
    const bool act = sub < 216;
    const int f = act ? sub : 215;
    const int fa = f / 36, rem = f - fa*36;
    const int fb = rem / 6, fc = rem - fb*6;
    const int baseK0 = fa*36 + fb*221 + fc*1334;   // pair (0,1): spect 2,3,4
    const int baseK1 = fa*6  + fb*221 + fc*1334;   // pair (1,2): spect 0,3,4
    const int baseK2 = rem   + fa*1334;            // pair (2,3): spect 0,1 (contig), 4
    const int baseK3 = f;                          // pair (3,4): spect 0,1,2 (contig)

    // SG mapping: fibers tid and tid+1024 (<1296); digits precomputed once
    int4 dg0, dg1;
    { int t = tid;        dg0.x = t % 6; t /= 6; dg0.y = t % 6; t /= 6; dg0.z = t % 6; dg0.w = t / 6; }
    { int t = tid + 1024; dg1.x = t % 6; t /= 6; dg1.y = t % 6; t /= 6; dg1.z = t % 6; dg1.w = t / 6; }
    const bool act1 = tid < 272;

    for (int l = 0; l < 4; ++l) {
        const h2* bsl = bs + l * 20 * 292;
        const h2* sgl = sg + l * 10 * 72;
        for (int hf = 0; hf < 2; ++hf) {
            const h2* bh = bsl + hf * 10 * 292;
            const h2* sh = sgl + hf * 5 * 72;
            // head peel: first half-layer passes 0,1,3 already applied in init
            const bool first = (l == 0) && (hf == 0);
            // tail skip: in the final half-layer, gates acting only on modes
            // {2,3,4} commute with the X0/X1 measurement -> drop them.
            const bool last = (l == 3) && (hf == 1);
            // rail order k = {0,2,1,3,0,2,1,3,0,2}
            if (!first) {
                pass_bs<6,1>     (bh + 0*292, psi, baseK0, act, qid);
                pass_bs<36,221>  (bh + 1*292, psi, baseK2, act, qid);
            }
            pass_bs<1,36>    (bh + 2*292, psi, baseK1, act, qid);
            if (!first)
                pass_bs<221,1334>(bh + 3*292, psi, baseK3, act, qid);
            pass_bs<6,1>     (bh + 4*292, psi, baseK0, act, qid);
            pass_bs<36,221>  (bh + 5*292, psi, baseK2, act, qid);
            pass_bs<1,36>    (bh + 6*292, psi, baseK1, act, qid);
            if (!last)
                pass_bs<221,1334>(bh + 7*292, psi, baseK3, act, qid);
            pass_bs<6,1>     (bh + 8*292, psi, baseK0, act, qid);
            if (!last)
                pass_bs<36,221>  (bh + 9*292, psi, baseK2, act, qid);
            if (hf == 0) {   // squeeze gates: parity-sparse
                pass_sg<6,    1,36,221,1334, true>(sh + 0*72, psi, dg0, dg1, act1);
                pass_sg<1,    6,36,221,1334, true>(sh + 1*72, psi, dg0, dg1, act1);
                pass_sg<36,   1,6,221,1334,  true>(sh + 2*72, psi, dg0, dg1, act1);
                pass_sg<221,  1,6,36,1334,   true>(sh + 3*72, psi, dg0, dg1, act1);
                pass_sg<1334, 1,6,36,221,    true>(sh + 4*72, psi, dg0, dg1, act1);
            } else {         // displacement gates: dense
                pass_sg<6,    1,36,221,1334, false>(sh + 0*72, psi, dg0, dg1, act1);
                pass_sg<1,    6,36,221,1334, false>(sh + 1*72, psi, dg0, dg1, act1);
                if (!last) {
                    pass_sg<36,   1,6,221,1334,  false>(sh + 2*72, psi, dg0, dg1, act1);
                    pass_sg<221,  1,6,36,1334,   false>(sh + 3*72, psi, dg0, dg1, act1);
                    pass_sg<1334, 1,6,36,221,    false>(sh + 4*72, psi, dg0, dg1, act1);
                }
            }
        }
    }

    // <psi| X psi> on modes 0 (stride 6) and 1 (stride 1); per-batch f32 accum
    float s0a = 0.f, s0b = 0.f, s1a = 0.f, s1b = 0.f;
    for (int fr = tid; fr < 1296; fr += 1024) {
        const int q0 = fr % 6;
        const int q1 = (fr / 6) % 6;
        const int q2 = (fr / 36) % 6;
        const int q3 = fr / 216;
        const int base0 = q0*1 + q1*36 + q2*221 + q3*1334;   // spectators of mode 0
        #pragma unroll
        for (int j = 0; j < 5; ++j) {
            const h4 a = psi[base0 + 6*j];
            const h4 c = psi[base0 + 6*(j+1)];
            const float w = sqrtf((float)(j+1));
            s0a = fmaf(w, fmaf((float)a.z, (float)c.z, (float)a.x*(float)c.x), s0a);
            s0b = fmaf(w, fmaf((float)a.w, (float)c.w, (float)a.y*(float)c.y), s0b);
        }
        const int base1 = q0*6 + q1*36 + q2*221 + q3*1334;   // spectators of mode 1
        #pragma unroll
        for (int j = 0; j < 5; ++j) {
            const h4 a = psi[base1 + j];
            const h4 c = psi[base1 + j + 1];
            const float w = sqrtf((float)(j+1));
            s1a = fmaf(w, fmaf((float)a.z, (float)c.z, (float)a.x*(float)c.x), s1a);
            s1b = fmaf(w, fmaf((float)a.w, (float)c.w, (float)a.y*(float)c.y), s1b);
        }
    }
    #pragma unroll
    for (int off = 32; off > 0; off >>= 1) {
        s0a += __shfl_down(s0a, off, 64);
        s0b += __shfl_down(s0b, off, 64);
        s1a += __shfl_down(s1a, off, 64);
        s1b += __shfl_down(s1b, off, 64);
    }
    if ((tid & 63) == 0) {
        const int w = tid >> 6;
        red[w*4 + 0] = s0a; red[w*4 + 1] = s1a;
        red[w*4 + 2] = s0b; red[w*4 + 3] = s1b;
    }
    __syncthreads();
    if (tid == 0) {
        float r0 = 0.f, r1 = 0.f, r2 = 0.f, r3 = 0.f;
        #pragma unroll
        for (int w = 0; w < 16; ++w) {
            r0 += red[w*4 + 0]; r1 += red[w*4 + 1];
            r2 += red[w*4 + 2]; r3 += red[w*4 + 3];
        }
        const int b0 = 2*b, b1 = 2*b + 1;
        out[b0*2 + 0] = 2.f * r0;
        out[b0*2 + 1] = 2.f * r1;
        if (b1 < B) {
            out[b1*2 + 0] = 2.f * r2;
            out[b1*2 + 1] = 2.f * r3;
        }
    }
}

// ---------------------------------------------------------------------------
extern "C" void kernel_launch(void* const* d_in, const int* in_sizes, int n_in,
                              void* d_out, int out_size, void* d_ws, size_t ws_size,
                              hipStream_t stream)
{
    const float* x    = (const float*)d_in[0];   // (B, 5)
    const float* lin  = (const float*)d_in[1];   // (4, 63)
    const float* act  = (const float*)d_in[2];   // (3, 5)
    const float* lact = (const float*)d_in[3];   // (5,)
    float* out = (float*)d_out;                  // (B, 2) float32

    const int B = in_sizes[0] / 5;

    // ws layout: 80 BS gates (292 h2) | 40 single gates (72 h2) | dcol f32
    h2*    bsh = (h2*)d_ws;
    h2*    sgh = bsh + 80*292;
    float* dc  = (float*)(sgh + 40*72);

    gates_kernel<<<dim3(81), dim3(256), 0, stream>>>(lin, act, lact, bsh, sgh);
    const int total = B * 5;
    dcol_kernel<<<dim3((total + 255)/256), dim3(256), 0, stream>>>(x, dc, total);
    qnet_kernel<<<dim3((B + 1) / 2), dim3(1024), 0, stream>>>(bsh, sgh, dc, out, B);
}

// Round 7
// 713.402 us; speedup vs baseline: 1.1654x; 1.0813x over previous
//
#include <hip/hip_runtime.h>

// QuantumDenseNet R19: qnet_kernel IDENTICAL to R18 (636us: head peel + tail
// skip + batch-pair h4 packing). This round attacks the persistent ~130us
// bench-vs-kernel gap (prep kernels + launches):
//  * gates_kernel + dcol_kernel FUSED into one prep_kernel (121 blocks) --
//    the two small grids overlap instead of serializing; one launch removed.
//  * expm cost matched to actual operator norms (params ~0.001 -> |H|<=0.02):
//    order-10 Taylor + 2 squarings (error <<1e-12, gates are f16-rounded
//    anyway; reference's order-16 + 6 squarings is indistinguishable).
//  * dcol via VECTOR Horner on column 0: w = e0; w = e0 + M w/k, k=30..1
//    (tridiagonal M, tail error ~1e-14) -- ~360 FMA/thread vs ~4000.

typedef float    vf2 __attribute__((ext_vector_type(2)));
typedef _Float16 h2  __attribute__((ext_vector_type(2)));
typedef _Float16 h4  __attribute__((ext_vector_type(4)));

__device__ __forceinline__ h2 pkfma(const h2 a, const h2 b, const h2 c) {
    return __builtin_elementwise_fma(a, b, c);
}

__device__ __forceinline__ void cmadd(float &ax, float &ay, const float2 u, const float2 v) {
    ax = fmaf(u.x, v.x, ax);
    ax = fmaf(-u.y, v.y, ax);
    ay = fmaf(u.x, v.y, ay);
    ay = fmaf(u.y, v.x, ay);
}

// block-diagonal structure of the 36x36 BS gate (total photon number n=0..10)
constexpr int BS_SN[11]  = {1,2,3,4,5,6,5,4,3,2,1};
constexpr int BS_OFF[11] = {0,1,5,14,30,55,91,116,132,141,145};
// mode strides (amp units): {6, 1, 36, 221, 1334}; max addr 7990

// runtime-indexed copy for prep_kernel packing + in-kernel head peel
__device__ const int d_BS_OFF[12] = {0,1,5,14,30,55,91,116,132,141,145,146};
__device__ const int d_BS_SN[11]  = {1,2,3,4,5,6,5,4,3,2,1};

// ---------------------------------------------------------------------------
// Fused prep kernel:
//   blocks 0..79  -> BS gates (order-10 Taylor, s=2 scaling/squaring) packed
//                    block-diag as BROADCAST h2 pairs {ur,ur},{ui,ui}
//   block  80     -> 40 single-mode combined gates (order-10, s=2)
//   blocks 81+    -> dcol: column 0 of expm via vector Horner (order 30, s=0)
// ---------------------------------------------------------------------------
__global__ void prep_kernel(const float* __restrict__ lin,
                            const float* __restrict__ act,
                            const float* __restrict__ lact,
                            const float* __restrict__ x,
                            h2* __restrict__ bsh,
                            h2* __restrict__ sgh,
                            float* __restrict__ dcol,
                            const int total)
{
    __shared__ float2 B0[1296];
    __shared__ float2 B1[1296];
    const int tid = threadIdx.x;

    if (blockIdx.x < 80) {
        const int g = blockIdx.x;
        const int l = g / 20;
        const int w = g % 20;
        const int q = w / 10;
        const int n = w % 10;
        const float theta = lin[l*63 + (q ? 29 : 0) + n];
        const float phi   = lin[l*63 + (q ? 39 : 10) + n];
        const float ts = theta * 0.25f;                 // s=2 scaling
        const float cp = cosf(phi), sp = sinf(phi);
        const float2 u  = make_float2( ts*cp, ts*sp);
        const float2 w2 = make_float2(-ts*cp, ts*sp);

        float2 *R = B0, *T = B1;
        for (int e = tid; e < 1296; e += 256)
            R[e] = make_float2((e % 37 == 0) ? 1.f : 0.f, 0.f);
        __syncthreads();

        for (int k = 10; k >= 1; --k) {
            const float invk = 1.f / (float)k;
            for (int e = tid; e < 1296; e += 256) {
                const int row = e / 36, c = e - row*36;
                const int i = row / 6, j = row - (row/6)*6;
                float ax = 0.f, ay = 0.f;
                if (i < 5 && j > 0) {
                    const float coef = sqrtf((float)((i+1)*j));
                    const float2 xv = R[(row+5)*36 + c];
                    const float px = u.x*xv.x - u.y*xv.y;
                    const float py = u.x*xv.y + u.y*xv.x;
                    ax = fmaf(coef, px, ax); ay = fmaf(coef, py, ay);
                }
                if (i > 0 && j < 5) {
                    const float coef = sqrtf((float)(i*(j+1)));
                    const float2 xv = R[(row-5)*36 + c];
                    const float px = w2.x*xv.x - w2.y*xv.y;
                    const float py = w2.x*xv.y + w2.y*xv.x;
                    ax = fmaf(coef, px, ax); ay = fmaf(coef, py, ay);
                }
                T[e] = make_float2(((row == c) ? 1.f : 0.f) + ax*invk, ay*invk);
            }
            __syncthreads();
            float2* tmp = R; R = T; T = tmp;
        }
        for (int s2 = 0; s2 < 2; ++s2) {                // s=2 squarings
            for (int e = tid; e < 1296; e += 256) {
                const int row = e / 36, c = e - row*36;
                float ax = 0.f, ay = 0.f;
                #pragma unroll 6
                for (int k = 0; k < 36; ++k)
                    cmadd(ax, ay, R[row*36 + k], R[k*36 + c]);
                T[e] = make_float2(ax, ay);
            }
            __syncthreads();
            float2* tmp = R; R = T; T = tmp;
        }
        for (int idx = tid; idx < 146; idx += 256) {
            int nn = 0;
            while (idx >= d_BS_OFF[nn+1]) ++nn;
            const int sn  = d_BS_SN[nn];
            const int rel = idx - d_BS_OFF[nn];
            const int p = rel / sn, qq = rel % sn;
            const int imin = (nn > 5) ? (nn - 5) : 0;
            const int row = 5*(imin + p)  + nn;
            const int col = 5*(imin + qq) + nn;
            const float2 z = R[row*36 + col];
            bsh[g*292 + 2*idx    ] = (h2){(_Float16)z.x, (_Float16)z.x};
            bsh[g*292 + 2*idx + 1] = (h2){(_Float16)z.y, (_Float16)z.y};
        }
    } else if (blockIdx.x == 80) {
        const int t = tid;
        if (t >= 40) return;
        const int l  = t / 10;
        const int gi = t % 10;
        float2 G[36];
        if (gi < 5) {
            // Sq[m] = squeeze(r) @ diag(e^{i rphi1 * n})  (parity-banded)
            const int m = gi;
            const float r    = lin[l*63 + 24 + m];
            const float rphi = (m < 4) ? lin[l*63 + 20 + m] : 0.f;
            float R[36], T[36];
            #pragma unroll
            for (int e = 0; e < 36; ++e) R[e] = (e % 7 == 0) ? 1.f : 0.f;
            float hp[4];
            #pragma unroll
            for (int i = 0; i < 4; ++i)
                hp[i] = 0.5f * r * sqrtf((float)((i+1)*(i+2))) * 0.25f;
            for (int k = 10; k >= 1; --k) {
                const float invk = 1.f / (float)k;
                #pragma unroll
                for (int i = 0; i < 6; ++i) {
                    #pragma unroll
                    for (int c = 0; c < 6; ++c) {
                        float a = 0.f;
                        if (i < 4)  a = fmaf( hp[i],   R[(i+2)*6 + c], a);
                        if (i >= 2) a = fmaf(-hp[i-2], R[(i-2)*6 + c], a);
                        T[i*6+c] = ((i == c) ? 1.f : 0.f) + a*invk;
                    }
                }
                #pragma unroll
                for (int e = 0; e < 36; ++e) R[e] = T[e];
            }
            for (int s2 = 0; s2 < 2; ++s2) {
                #pragma unroll
                for (int i = 0; i < 6; ++i) {
                    #pragma unroll
                    for (int c = 0; c < 6; ++c) {
                        float a = 0.f;
                        #pragma unroll
                        for (int k = 0; k < 6; ++k) a = fmaf(R[i*6+k], R[k*6+c], a);
                        T[i*6+c] = a;
                    }
                }
                #pragma unroll
                for (int e = 0; e < 36; ++e) R[e] = T[e];
            }
            #pragma unroll
            for (int c = 0; c < 6; ++c) {
                const float cc = cosf(rphi * (float)c), ss = sinf(rphi * (float)c);
                #pragma unroll
                for (int o = 0; o < 6; ++o)
                    G[o*6 + c] = make_float2(R[o*6+c]*cc, R[o*6+c]*ss);
            }
        } else {
            // Dp[m] = diag(e^{i kap n^2}) @ disp(dr,dp) @ diag(e^{i rphi2 n})
            const int m = gi - 5;
            const float dr   = lin[l*63 + 53 + m];
            const float dp   = lin[l*63 + 58 + m];
            const float rphi = (m < 4) ? lin[l*63 + 49 + m] : 0.f;
            const float kap  = (l < 3) ? act[l*5 + m] : ((m < 2) ? lact[m] : 0.f);
            const float2 al = make_float2(dr * cosf(dp), dr * sinf(dp));
            float2 R[36], T[36];
            #pragma unroll
            for (int e = 0; e < 36; ++e)
                R[e] = make_float2((e % 7 == 0) ? 1.f : 0.f, 0.f);
            float2 cm[6], cpb[6];
            #pragma unroll
            for (int i = 0; i < 6; ++i) {
                const float sm  = sqrtf((float)i)     * 0.25f;
                const float sp2 = sqrtf((float)(i+1)) * 0.25f;
                cm[i]  = make_float2( al.x*sm,  al.y*sm);
                cpb[i] = make_float2(-al.x*sp2, al.y*sp2);
            }
            for (int k = 10; k >= 1; --k) {
                const float invk = 1.f / (float)k;
                #pragma unroll
                for (int i = 0; i < 6; ++i) {
                    #pragma unroll
                    for (int c = 0; c < 6; ++c) {
                        float ax = 0.f, ay = 0.f;
                        if (i >= 1) cmadd(ax, ay, cm[i],  R[(i-1)*6 + c]);
                        if (i < 5)  cmadd(ax, ay, cpb[i], R[(i+1)*6 + c]);
                        T[i*6+c] = make_float2(((i == c) ? 1.f : 0.f) + ax*invk, ay*invk);
                    }
                }
                #pragma unroll
                for (int e = 0; e < 36; ++e) R[e] = T[e];
            }
            for (int s2 = 0; s2 < 2; ++s2) {
                #pragma unroll
                for (int i = 0; i < 6; ++i) {
                    #pragma unroll
                    for (int c = 0; c < 6; ++c) {
                        float ax = 0.f, ay = 0.f;
                        #pragma unroll
                        for (int k = 0; k < 6; ++k) cmadd(ax, ay, R[i*6+k], R[k*6+c]);
                        T[i*6+c] = make_float2(ax, ay);
                    }
                }
                #pragma unroll
                for (int e = 0; e < 36; ++e) R[e] = T[e];
            }
            #pragma unroll
            for (int o = 0; o < 6; ++o) {
                const float ko = kap * (float)(o*o);
                const float2 kp = make_float2(cosf(ko), sinf(ko));
                #pragma unroll
                for (int c = 0; c < 6; ++c) {
                    const float rc = rphi * (float)c;
                    const float2 rp = make_float2(cosf(rc), sinf(rc));
                    const float2 z = R[o*6 + c];
                    const float2 t1 = make_float2(kp.x*z.x - kp.y*z.y, kp.x*z.y + kp.y*z.x);
                    G[o*6 + c] = make_float2(t1.x*rp.x - t1.y*rp.y, t1.x*rp.y + t1.y*rp.x);
                }
            }
        }
        h2* outp = sgh + (l*10 + gi)*72;
        #pragma unroll
        for (int e = 0; e < 36; ++e) {
            outp[2*e    ] = (h2){(_Float16)G[e].x, (_Float16)G[e].x};
            outp[2*e + 1] = (h2){(_Float16)G[e].y, (_Float16)G[e].y};
        }
    } else {
        // dcol: column 0 of expm(x(A†-A)) via vector Horner, order 30, s=0.
        // (MÂ·w)[i] = x(sqrt(i) w[i-1] - sqrt(i+1) w[i+1]); w = e0 + M w / k.
        const int i = (blockIdx.x - 81) * 256 + tid;
        if (i >= total) return;
        const float xv = x[i];
        float a[5];
        #pragma unroll
        for (int j = 0; j < 5; ++j) a[j] = xv * sqrtf((float)(j+1));
        float w[6];
        #pragma unroll
        for (int j = 0; j < 6; ++j) w[j] = (j == 0) ? 1.f : 0.f;
        for (int k = 30; k >= 1; --k) {
            const float invk = 1.f / (float)k;
            float t[6];
            #pragma unroll
            for (int r = 0; r < 6; ++r) {
                float acc = 0.f;
                if (r >= 1) acc = fmaf( a[r-1], w[r-1], acc);
                if (r < 5)  acc = fmaf(-a[r],   w[r+1], acc);
                t[r] = ((r == 0) ? 1.f : 0.f) + acc*invk;
            }
            #pragma unroll
            for (int j = 0; j < 6; ++j) w[j] = t[j];
        }
        #pragma unroll
        for (int j = 0; j < 6; ++j) dcol[i*6 + j] = w[j];
    }
}

// ---------------------------------------------------------------------------
// Main kernel building blocks (batch-pair packed, 8B complex amplitudes)
// ---------------------------------------------------------------------------

// rows [R0,R1) of photon block n of one BS pass. One ds_read_b64 per input
// amplitude; lo h2 = re{b0,b1}, hi h2 = im{b0,b1}. Broadcast gates:
//   aR += ur*vR - ui*vI ; aI += ur*vI + ui*vR
template<int SA, int SB, int n, int R0, int R1>
__device__ __forceinline__ void bs_rows(const h2* __restrict__ U,
                                        h4* __restrict__ psi,
                                        const int base, const bool act)
{
    constexpr int sn = BS_SN[n], uoff = BS_OFF[n];
    constexpr int imin = (n > 5) ? (n - 5) : 0;
    if (!act) return;
    h2 vR[sn], vI[sn];
    #pragma unroll
    for (int q = 0; q < sn; ++q) {
        const int c = 5*(imin + q) + n;
        const h4 v = psi[base + (c/6)*SA + (c%6)*SB];
        vR[q] = (h2){v.x, v.y};
        vI[q] = (h2){v.z, v.w};
    }
    h2 oR[R1-R0], oI[R1-R0];
    #pragma unroll
    for (int p = R0; p < R1; ++p) {
        const h2* Up = U + 2*(uoff + p*sn);
        h2 ur = Up[0], ui = Up[1];
        h2 aR = ur * vR[0];
        aR = pkfma(-ui, vI[0], aR);
        h2 aI = ur * vI[0];
        aI = pkfma(ui, vR[0], aI);
        #pragma unroll
        for (int q = 1; q < sn; ++q) {
            ur = Up[2*q]; ui = Up[2*q + 1];
            aR = pkfma(ur, vR[q], aR);
            aR = pkfma(-ui, vI[q], aR);
            aI = pkfma(ur, vI[q], aI);
            aI = pkfma(ui, vR[q], aI);
        }
        oR[p-R0] = aR; oI[p-R0] = aI;
    }
    #pragma unroll
    for (int p = R0; p < R1; ++p) {
        const int c = 5*(imin + p) + n;
        const h2 r = oR[p-R0], m = oI[p-R0];
        psi[base + (c/6)*SA + (c%6)*SB] = (h4){r.x, r.y, m.x, m.y};
    }
}

// BS pass: 4 wave-aligned quarters of 256 threads; whole-block groups (no row
// splits -- those race on read-vs-write of shared block inputs).
// packed-cMAC: q0={5}=36, q1={4,2,1}=38, q2={6,8,9}=38, q3={3,7,0,10}=34.
// (max quarter = 38 is optimal for any whole-block partition.)
template<int SA, int SB>
__device__ __forceinline__ void pass_bs(const h2* __restrict__ U,
                                        h4* __restrict__ psi,
                                        const int base, const bool act, const int qid)
{
    if (qid == 0) {
        bs_rows<SA,SB,5,0,6>(U, psi, base, act);
    } else if (qid == 1) {
        bs_rows<SA,SB,4,0,5>(U, psi, base, act);
        bs_rows<SA,SB,2,0,3>(U, psi, base, act);
        bs_rows<SA,SB,1,0,2>(U, psi, base, act);
    } else if (qid == 2) {
        bs_rows<SA,SB,6,0,5>(U, psi, base, act);
        bs_rows<SA,SB,8,0,3>(U, psi, base, act);
        bs_rows<SA,SB,9,0,2>(U, psi, base, act);
    } else {
        bs_rows<SA,SB,3,0,4>(U, psi, base, act);
        bs_rows<SA,SB,7,0,4>(U, psi, base, act);
        bs_rows<SA,SB,0,0,1>(U, psi, base, act);
        bs_rows<SA,SB,10,0,1>(U, psi, base, act);
    }
    __syncthreads();
}

// one single-mode-gate fiber (6 amplitudes, stride SM), 8B-packed
template<int SM, bool SP>
__device__ __forceinline__ void sg_fiber(const h2* __restrict__ G,
                                         h4* __restrict__ psi,
                                         const int base)
{
    h2 vR[6], vI[6];
    #pragma unroll
    for (int k = 0; k < 6; ++k) {
        const h4 v = psi[base + k*SM];
        vR[k] = (h2){v.x, v.y};
        vI[k] = (h2){v.z, v.w};
    }
    h2 oR[6], oI[6];
    #pragma unroll
    for (int o = 0; o < 6; ++o) {
        const int k0 = SP ? (o & 1) : 0;
        const int st = SP ? 2 : 1;
        h2 ur = G[2*(o*6 + k0)], ui = G[2*(o*6 + k0) + 1];
        h2 aR = ur * vR[k0];
        aR = pkfma(-ui, vI[k0], aR);
        h2 aI = ur * vI[k0];
        aI = pkfma(ui, vR[k0], aI);
        #pragma unroll
        for (int k = k0 + st; k < 6; k += st) {
            ur = G[2*(o*6 + k)]; ui = G[2*(o*6 + k) + 1];
            aR = pkfma(ur, vR[k], aR);
            aR = pkfma(-ui, vI[k], aR);
            aI = pkfma(ur, vI[k], aI);
            aI = pkfma(ui, vR[k], aI);
        }
        oR[o] = aR; oI[o] = aI;
    }
    #pragma unroll
    for (int o = 0; o < 6; ++o)
        psi[base + o*SM] = (h4){oR[o].x, oR[o].y, oI[o].x, oI[o].y};
}

// single-mode gate pass: 1296 fibers over 1024 threads (ragged second round).
// dg0/dg1 = precomputed base-6 digits of fiber ids tid and tid+1024.
template<int SM, int S0, int S1, int S2, int S3, bool SP>
__device__ __forceinline__ void pass_sg(const h2* __restrict__ G,
                                        h4* __restrict__ psi,
                                        const int4 dg0, const int4 dg1, const bool act1)
{
    {
        const int base = dg0.x*S0 + dg0.y*S1 + dg0.z*S2 + dg0.w*S3;
        sg_fiber<SM,SP>(G, psi, base);
    }
    if (act1) {
        const int base = dg1.x*S0 + dg1.y*S1 + dg1.z*S2 + dg1.w*S3;
        sg_fiber<SM,SP>(G, psi, base);
    }
    __syncthreads();
}

__global__ __launch_bounds__(1024, 8)
void qnet_kernel(const h2* __restrict__ bs,
                 const h2* __restrict__ sg,
                 const float* __restrict__ dcol,
                 float* __restrict__ out,
                 const int B)
{
    // addr = 6*i0 + i1 + 36*i2 + 221*i3 + 1334*i4 (max 7990), 8B per amplitude
    __shared__ __align__(16) h4 psi[7992];      // 63,936 B
    __shared__ float stf[60];
    __shared__ float red[64];
    // head-peel staging (f32): psi01/psi23 per batch (36), f234 per batch (216)
    __shared__ float2 ps01[2][36];
    __shared__ float2 ps23[2][36];
    __shared__ float2 f234[2][216];

    const int tid = threadIdx.x;
    const int b   = blockIdx.x;          // batch pair (2b, 2b+1)

    const int lim = B * 30;
    if (tid < 60) stf[tid] = (b*60 + tid < lim) ? dcol[b*60 + tid] : 0.f;
    __syncthreads();

    // ---- head peel round A: psi01 = BS01@(d0⊗d1), psi23 = BS23@(d2⊗d3) ----
    // gates: layer0/hf0 pass0 (rail0) at bs+0*292, pass1 (rail2) at bs+1*292
    if (tid < 144) {
        const int part = tid / 36;       // 0:ps01 b0, 1:ps01 b1, 2:ps23 b0, 3:ps23 b1
        const int idx  = tid - part*36;
        const int p    = part & 1;
        const bool m01 = part < 2;
        const int i = idx / 6, j = idx - (idx/6)*6;
        const int n = i + j;
        const int imin = (n > 5) ? (n - 5) : 0;
        const int sn   = d_BS_SN[n];
        const int prow = i - imin;
        const h2* U = bs + (m01 ? 0 : 1)*292 + 2*(d_BS_OFF[n] + prow*sn);
        const float* dA = stf + p*30 + (m01 ? 0 : 12);
        const float* dB = dA + 6;
        float ar = 0.f, ai = 0.f;
        for (int q = 0; q < sn; ++q) {
            const float ur = (float)U[2*q].x, ui = (float)U[2*q+1].x;
            const float dd = dA[imin+q] * dB[n-imin-q];
            ar = fmaf(ur, dd, ar); ai = fmaf(ui, dd, ai);
        }
        if (m01) ps01[p][idx] = make_float2(ar, ai);
        else     ps23[p][idx] = make_float2(ar, ai);
    }
    __syncthreads();

    // ---- head peel round B: f234 = BS34@(psi23⊗d4) (pass3/rail3 commutes
    //      with pass2/rail1, so it legally reorders ahead of it) ----
    if (tid < 432) {
        const int p  = tid / 216;
        const int r  = tid - p*216;
        const int i2 = r / 36, i34 = r - i2*36;
        const int i3 = i34 / 6, i4 = i34 - i3*6;
        const int n  = i3 + i4;
        const int imin = (n > 5) ? (n - 5) : 0;
        const int sn   = d_BS_SN[n];
        const int prow = i3 - imin;
        const h2* U = bs + 3*292 + 2*(d_BS_OFF[n] + prow*sn);
        const float* d4 = stf + p*30 + 24;
        float ar = 0.f, ai = 0.f;
        for (int q = 0; q < sn; ++q) {
            const float ur = (float)U[2*q].x, ui = (float)U[2*q+1].x;
            const float2 w23 = ps23[p][i2*6 + (imin+q)];
            const float dd = d4[n-imin-q];
            ar = fmaf(dd, ur*w23.x - ui*w23.y, ar);
            ai = fmaf(dd, ur*w23.y + ui*w23.x, ai);
        }
        f234[p][r] = make_float2(ar, ai);
    }
    __syncthreads();

    // ---- init: psi = psi01 ⊗ f234 (complex product, rounded once to f16) ----
    for (int e = tid; e < 7776; e += 1024) {
        int t = e;
        const int i4 = t % 6; t /= 6;
        const int i3 = t % 6; t /= 6;
        const int i2 = t % 6; t /= 6;
        const int i1 = t % 6; t /= 6;
        const int i0 = t;
        const int addr = 6*i0 + i1 + 36*i2 + 221*i3 + 1334*i4;
        const int i01 = i0*6 + i1;
        const int r   = i2*36 + i3*6 + i4;
        const float2 a0 = ps01[0][i01], b0 = f234[0][r];
        const float2 a1 = ps01[1][i01], b1 = f234[1][r];
        const float v0r = a0.x*b0.x - a0.y*b0.y, v0i = a0.x*b0.y + a0.y*b0.x;
        const float v1r = a1.x*b1.x - a1.y*b1.y, v1i = a1.x*b1.y + a1.y*b1.x;
        psi[addr] = (h4){(_Float16)v0r, (_Float16)v1r, (_Float16)v0i, (_Float16)v1i};
    }
    __syncthreads();

    // BS mapping: 4 quarters of 256; sub<216 active; fiber f = sub
    const int sub = tid & 255;
    const int qid = __builtin_amdgcn_readfirstlane(tid >> 8);   // wave-uniform
    const bool act = sub < 216;
    const int f = act ? sub : 215;
    const int fa = f / 36, rem = f - fa*36;
    const int fb = rem / 6, fc = rem - fb*6;
    const int baseK0 = fa*36 + fb*221 + fc*1334;   // pair (0,1): spect 2,3,4
    const int baseK1 = fa*6  + fb*221 + fc*1334;   // pair (1,2): spect 0,3,4
    const int baseK2 = rem   + fa*1334;            // pair (2,3): spect 0,1 (contig), 4
    const int baseK3 = f;                          // pair (3,4): spect 0,1,2 (contig)

    // SG mapping: fibers tid and tid+1024 (<1296); digits precomputed once
    int4 dg0, dg1;
    { int t = tid;        dg0.x = t % 6; t /= 6; dg0.y = t % 6; t /= 6; dg0.z = t % 6; dg0.w = t / 6; }
    { int t = tid + 1024; dg1.x = t % 6; t /= 6; dg1.y = t % 6; t /= 6; dg1.z = t % 6; dg1.w = t / 6; }
    const bool act1 = tid < 272;

    for (int l = 0; l < 4; ++l) {
        const h2* bsl = bs + l * 20 * 292;
        const h2* sgl = sg + l * 10 * 72;
        for (int hf = 0; hf < 2; ++hf) {
            const h2* bh = bsl + hf * 10 * 292;
            const h2* sh = sgl + hf * 5 * 72;
            // head peel: first half-layer passes 0,1,3 already applied in init
            const bool first = (l == 0) && (hf == 0);
            // tail skip: in the final half-layer, gates acting only on modes
            // {2,3,4} commute with the X0/X1 measurement -> drop them.
            const bool last = (l == 3) && (hf == 1);
            // rail order k = {0,2,1,3,0,2,1,3,0,2}
            if (!first) {
                pass_bs<6,1>     (bh + 0*292, psi, baseK0, act, qid);
                pass_bs<36,221>  (bh + 1*292, psi, baseK2, act, qid);
            }
            pass_bs<1,36>    (bh + 2*292, psi, baseK1, act, qid);
            if (!first)
                pass_bs<221,1334>(bh + 3*292, psi, baseK3, act, qid);
            pass_bs<6,1>     (bh + 4*292, psi, baseK0, act, qid);
            pass_bs<36,221>  (bh + 5*292, psi, baseK2, act, qid);
            pass_bs<1,36>    (bh + 6*292, psi, baseK1, act, qid);
            if (!last)
                pass_bs<221,1334>(bh + 7*292, psi, baseK3, act, qid);
            pass_bs<6,1>     (bh + 8*292, psi, baseK0, act, qid);
            if (!last)
                pass_bs<36,221>  (bh + 9*292, psi, baseK2, act, qid);
            if (hf == 0) {   // squeeze gates: parity-sparse
                pass_sg<6,    1,36,221,1334, true>(sh + 0*72, psi, dg0, dg1, act1);
                pass_sg<1,    6,36,221,1334, true>(sh + 1*72, psi, dg0, dg1, act1);
                pass_sg<36,   1,6,221,1334,  true>(sh + 2*72, psi, dg0, dg1, act1);
                pass_sg<221,  1,6,36,1334,   true>(sh + 3*72, psi, dg0, dg1, act1);
                pass_sg<1334, 1,6,36,221,    true>(sh + 4*72, psi, dg0, dg1, act1);
            } else {         // displacement gates: dense
                pass_sg<6,    1,36,221,1334, false>(sh + 0*72, psi, dg0, dg1, act1);
                pass_sg<1,    6,36,221,1334, false>(sh + 1*72, psi, dg0, dg1, act1);
                if (!last) {
                    pass_sg<36,   1,6,221,1334,  false>(sh + 2*72, psi, dg0, dg1, act1);
                    pass_sg<221,  1,6,36,1334,   false>(sh + 3*72, psi, dg0, dg1, act1);
                    pass_sg<1334, 1,6,36,221,    false>(sh + 4*72, psi, dg0, dg1, act1);
                }
            }
        }
    }

    // <psi| X psi> on modes 0 (stride 6) and 1 (stride 1); per-batch f32 accum
    float s0a = 0.f, s0b = 0.f, s1a = 0.f, s1b = 0.f;
    for (int fr = tid; fr < 1296; fr += 1024) {
        const int q0 = fr % 6;
        const int q1 = (fr / 6) % 6;
        const int q2 = (fr / 36) % 6;
        const int q3 = fr / 216;
        const int base0 = q0*1 + q1*36 + q2*221 + q3*1334;   // spectators of mode 0
        #pragma unroll
        for (int j = 0; j < 5; ++j) {
            const h4 a = psi[base0 + 6*j];
            const h4 c = psi[base0 + 6*(j+1)];
            const float w = sqrtf((float)(j+1));
            s0a = fmaf(w, fmaf((float)a.z, (float)c.z, (float)a.x*(float)c.x), s0a);
            s0b = fmaf(w, fmaf((float)a.w, (float)c.w, (float)a.y*(float)c.y), s0b);
        }
        const int base1 = q0*6 + q1*36 + q2*221 + q3*1334;   // spectators of mode 1
        #pragma unroll
        for (int j = 0; j < 5; ++j) {
            const h4 a = psi[base1 + j];
            const h4 c = psi[base1 + j + 1];
            const float w = sqrtf((float)(j+1));
            s1a = fmaf(w, fmaf((float)a.z, (float)c.z, (float)a.x*(float)c.x), s1a);
            s1b = fmaf(w, fmaf((float)a.w, (float)c.w, (float)a.y*(float)c.y), s1b);
        }
    }
    #pragma unroll
    for (int off = 32; off > 0; off >>= 1) {
        s0a += __shfl_down(s0a, off, 64);
        s0b += __shfl_down(s0b, off, 64);
        s1a += __shfl_down(s1a, off, 64);
        s1b += __shfl_down(s1b, off, 64);
    }
    if ((tid & 63) == 0) {
        const int w = tid >> 6;
        red[w*4 + 0] = s0a; red[w*4 + 1] = s1a;
        red[w*4 + 2] = s0b; red[w*4 + 3] = s1b;
    }
    __syncthreads();
    if (tid == 0) {
        float r0 = 0.f, r1 = 0.f, r2 = 0.f, r3 = 0.f;
        #pragma unroll
        for (int w = 0; w < 16; ++w) {
            r0 += red[w*4 + 0]; r1 += red[w*4 + 1];
            r2 += red[w*4 + 2]; r3 += red[w*4 + 3];
        }
        const int b0 = 2*b, b1 = 2*b + 1;
        out[b0*2 + 0] = 2.f * r0;
        out[b0*2 + 1] = 2.f * r1;
        if (b1 < B) {
            out[b1*2 + 0] = 2.f * r2;
            out[b1*2 + 1] = 2.f * r3;
        }
    }
}

// ---------------------------------------------------------------------------
extern "C" void kernel_launch(void* const* d_in, const int* in_sizes, int n_in,
                              void* d_out, int out_size, void* d_ws, size_t ws_size,
                              hipStream_t stream)
{
    const float* x    = (const float*)d_in[0];   // (B, 5)
    const float* lin  = (const float*)d_in[1];   // (4, 63)
    const float* act  = (const float*)d_in[2];   // (3, 5)
    const float* lact = (const float*)d_in[3];   // (5,)
    float* out = (float*)d_out;                  // (B, 2) float32

    const int B = in_sizes[0] / 5;

    // ws layout: 80 BS gates (292 h2) | 40 single gates (72 h2) | dcol f32
    h2*    bsh = (h2*)d_ws;
    h2*    sgh = bsh + 80*292;
    float* dc  = (float*)(sgh + 40*72);

    const int total  = B * 5;
    const int nprep  = 81 + (total + 255) / 256;
    prep_kernel<<<dim3(nprep), dim3(256), 0, stream>>>(lin, act, lact, x, bsh, sgh, dc, total);
    qnet_kernel<<<dim3((B + 1) / 2), dim3(1024), 0, stream>>>(bsh, sgh, dc, out, B);
}